// Round 1
// baseline (1863.474 us; speedup 1.0000x reference)
//
#include <hip/hip_runtime.h>

#define NROW  16384
#define DD    512
#define VOCAB 8192
#define VSPLIT 2
#define VHALF (VOCAB / VSPLIT)
#define BM 128
#define BN 256
#define BK 32
#define NT 512

// ---------------- ws layout (float/int words) ----------------
// xnorm  [NROW]          @ 0
// xrcp   [NROW]          @ 16384      (unused this round, reserved)
// cbnorm [VOCAB]         @ 32768
// cbrcp  [VOCAB]         @ 40960
// candval[VSPLIT][NROW][2] @ 49152    (floats)
// candidx[VSPLIT][NROW][2] @ 114688   (ints)
// maxsim [NROW]          @ 180224
// counts [VOCAB] (int)   @ 196608
#define WS_XNORM   0
#define WS_XRCP    16384
#define WS_CBNORM  32768
#define WS_CBRCP   40960
#define WS_CANDV   49152
#define WS_CANDI   114688
#define WS_MAXSIM  180224
#define WS_COUNTS  196608

#define OUT_IDX   ((size_t)NROW * DD)            // 8388608
#define OUT_ENT   (OUT_IDX + NROW)               // 8404992
#define OUT_MEAN  (OUT_ENT + 1)                  // 8404993

// ---------------- row L2 norms (one wave per row) ----------------
__global__ void eq_rownorm(const float* __restrict__ src, float* __restrict__ nrm,
                           float* __restrict__ rcp, int nrows) {
    int row = blockIdx.x;
    if (row >= nrows) return;
    int l = threadIdx.x;                  // 64 threads = 1 wave
    const float* p = src + (size_t)row * DD;
    float s = 0.f;
#pragma unroll
    for (int i = 0; i < 2; ++i) {
        float4 v = *(const float4*)(p + i * 256 + l * 4);
        s += v.x * v.x + v.y * v.y + v.z * v.z + v.w * v.w;
    }
#pragma unroll
    for (int off = 32; off > 0; off >>= 1) s += __shfl_down(s, off, 64);
    if (l == 0) {
        float n = fmaxf(sqrtf(s), 1e-12f);   // ref: max(norm, EPS)
        nrm[row] = n;
        rcp[row] = 1.0f / n;                 // approx scale for pass-1 only
    }
}

// ---------------- pass 1: fp32 GEMM + per-row top-2 candidates ----------------
// grid (NROW/BM, VSPLIT), block NT=512. Each block: 128 rows x one vocab half.
// A staged raw (row scale irrelevant to per-row ranking); B scaled by 1/||c||.
__global__ __launch_bounds__(NT, 2) void eq_gemm_top2(
    const float* __restrict__ x, const float* __restrict__ cb,
    const float* __restrict__ cbrcp,
    float* __restrict__ candval, int* __restrict__ candidx) {
    __shared__ float As[BK][BM + 4];   // 16.9 KB
    __shared__ float Bs[BK][BN + 4];   // 33.3 KB
    const int tid = threadIdx.x;
    const int tx = tid & 31;           // col group 0..31 (8 cols each)
    const int ty = tid >> 5;           // row group 0..15 (8 rows each)
    const int row0 = blockIdx.x * BM;
    const int vbase = blockIdx.y * VHALF;

    float t1v[8], t2v[8]; int t1i[8], t2i[8];
#pragma unroll
    for (int i = 0; i < 8; ++i) {
        t1v[i] = -3.0e38f; t2v[i] = -3.0e38f; t1i[i] = 1 << 30; t2i[i] = 1 << 30;
    }

    for (int vc = 0; vc < VHALF; vc += BN) {
        float acc[8][8];
#pragma unroll
        for (int i = 0; i < 8; ++i)
#pragma unroll
            for (int j = 0; j < 8; ++j) acc[i][j] = 0.f;

        for (int kt = 0; kt < DD; kt += BK) {
            // stage A: 128x32 floats, raw x
#pragma unroll
            for (int p = 0; p < 2; ++p) {
                int id = tid + p * NT;
                int r = id >> 3, kg = id & 7;
                float4 v = *(const float4*)(x + (size_t)(row0 + r) * DD + kt + kg * 4);
                As[kg * 4 + 0][r] = v.x;
                As[kg * 4 + 1][r] = v.y;
                As[kg * 4 + 2][r] = v.z;
                As[kg * 4 + 3][r] = v.w;
            }
            // stage B: 256x32 floats, cb * (1/||c||)
#pragma unroll
            for (int p = 0; p < 4; ++p) {
                int id = tid + p * NT;
                int vv = id >> 3, kg = id & 7;
                int col = vbase + vc + vv;
                float4 v = *(const float4*)(cb + (size_t)col * DD + kt + kg * 4);
                float rn = cbrcp[col];
                Bs[kg * 4 + 0][vv] = v.x * rn;
                Bs[kg * 4 + 1][vv] = v.y * rn;
                Bs[kg * 4 + 2][vv] = v.z * rn;
                Bs[kg * 4 + 3][vv] = v.w * rn;
            }
            __syncthreads();
#pragma unroll 8
            for (int k = 0; k < BK; ++k) {
                float4 a0 = *(const float4*)&As[k][ty * 8];
                float4 a1 = *(const float4*)&As[k][ty * 8 + 4];
                float4 b0 = *(const float4*)&Bs[k][tx * 8];
                float4 b1 = *(const float4*)&Bs[k][tx * 8 + 4];
                float a[8] = {a0.x, a0.y, a0.z, a0.w, a1.x, a1.y, a1.z, a1.w};
                float b[8] = {b0.x, b0.y, b0.z, b0.w, b1.x, b1.y, b1.z, b1.w};
#pragma unroll
                for (int i = 0; i < 8; ++i)
#pragma unroll
                    for (int j = 0; j < 8; ++j)
                        acc[i][j] = fmaf(a[i], b[j], acc[i][j]);
            }
            __syncthreads();
        }
        // fold this col-chunk into the per-thread top-2 (branchless)
#pragma unroll
        for (int i = 0; i < 8; ++i) {
#pragma unroll
            for (int j = 0; j < 8; ++j) {
                float v = acc[i][j];
                int idx = vbase + vc + tx * 8 + j;
                bool b1 = v > t1v[i];
                bool b2 = v > t2v[i];
                t2v[i] = b1 ? t1v[i] : (b2 ? v : t2v[i]);
                t2i[i] = b1 ? t1i[i] : (b2 ? idx : t2i[i]);
                t1v[i] = b1 ? v : t1v[i];
                t1i[i] = b1 ? idx : t1i[i];
            }
        }
    }
    // merge top-2 across the 32 tx-lanes (butterfly stays within each 32-half)
#pragma unroll
    for (int off = 1; off < 32; off <<= 1) {
#pragma unroll
        for (int i = 0; i < 8; ++i) {
            float o1v = __shfl_xor(t1v[i], off, 64);
            int   o1i = __shfl_xor(t1i[i], off, 64);
            float o2v = __shfl_xor(t2v[i], off, 64);
            int   o2i = __shfl_xor(t2i[i], off, 64);
            bool fw = (t1v[i] > o1v) || (t1v[i] == o1v && t1i[i] < o1i);
            float n1v = fw ? t1v[i] : o1v;  int n1i = fw ? t1i[i] : o1i;
            float c2v = fw ? o1v : t1v[i];  int c2i = fw ? o1i : t1i[i];  // loser of tops
            float d2v = fw ? t2v[i] : o2v;  int d2i = fw ? t2i[i] : o2i;  // winner's 2nd
            bool sec = (c2v > d2v) || (c2v == d2v && c2i < d2i);
            t1v[i] = n1v; t1i[i] = n1i;
            t2v[i] = sec ? c2v : d2v;
            t2i[i] = sec ? c2i : d2i;
        }
    }
    if (tx == 0) {
#pragma unroll
        for (int i = 0; i < 8; ++i) {
            int row = row0 + ty * 8 + i;
            size_t base = ((size_t)blockIdx.y * NROW + row) * 2;
            candval[base + 0] = t1v[i]; candidx[base + 0] = t1i[i];
            candval[base + 1] = t2v[i]; candidx[base + 1] = t2i[i];
        }
    }
}

// ---------------- finalize: fp64 rescore of 4 candidates, gather, histogram ----------------
// block 256 = 4 waves, one row per wave; grid NROW/4
__global__ void eq_finalize(
    const float* __restrict__ x, const float* __restrict__ cb,
    const float* __restrict__ xnorm, const float* __restrict__ cbnorm,
    const int* __restrict__ candidx,
    float* __restrict__ out, float* __restrict__ maxsim, int* __restrict__ counts) {
    int w = threadIdx.x >> 6;
    int l = threadIdx.x & 63;
    int row = blockIdx.x * 4 + w;

    int cidx[4];
#pragma unroll
    for (int s = 0; s < 2; ++s)
#pragma unroll
        for (int t = 0; t < 2; ++t)
            cidx[s * 2 + t] = candidx[((size_t)s * NROW + row) * 2 + t];

    float xn = xnorm[row];
    float cbn[4];
#pragma unroll
    for (int c = 0; c < 4; ++c) cbn[c] = cbnorm[cidx[c]];

    double acc[4] = {0.0, 0.0, 0.0, 0.0};
#pragma unroll
    for (int p = 0; p < 8; ++p) {
        int e = p * 64 + l;
        float xe = x[(size_t)row * DD + e] / xn;        // exact fp32 rounding, as ref
        double xd = (double)xe;
#pragma unroll
        for (int c = 0; c < 4; ++c) {
            float ce = cb[(size_t)cidx[c] * DD + e] / cbn[c];  // exact fp32 rounding
            acc[c] += xd * (double)ce;
        }
    }
#pragma unroll
    for (int off = 32; off > 0; off >>= 1)
#pragma unroll
        for (int c = 0; c < 4; ++c) acc[c] += __shfl_down(acc[c], off, 64);

    int bidx = 0;
    if (l == 0) {
        double bv = -2.0; int bi = 1 << 30;
#pragma unroll
        for (int c = 0; c < 4; ++c) {
            double v = acc[c]; int ii = cidx[c];
            bool better = (v > bv) || (v == bv && ii < bi);
            bv = better ? v : bv;
            bi = better ? ii : bi;
        }
        bidx = bi;
        out[OUT_IDX + row] = (float)bi;      // indices as float
        maxsim[row] = (float)bv;
        atomicAdd(counts + bi, 1);
    }
    bidx = __shfl(bidx, 0, 64);
    // z_q gather: raw codebook row
    const float4* src = (const float4*)(cb + (size_t)bidx * DD);
    float4* dst = (float4*)(out + (size_t)row * DD);
    dst[l] = src[l];
    dst[l + 64] = src[l + 64];
}

// ---------------- entropy + mean ----------------
__global__ void eq_entropy_mean(const int* __restrict__ counts,
                                const float* __restrict__ maxsim,
                                float* __restrict__ out) {
    __shared__ float red[16];
    int tid = threadIdx.x;   // 1024
    float s = 0.f;
    for (int b = tid; b < VOCAB; b += 1024) {
        int c = counts[b];
        if (c > 0) {
            float p = (float)c * (1.0f / 16384.0f);
            s += p * logf(p);
        }
    }
#pragma unroll
    for (int off = 32; off > 0; off >>= 1) s += __shfl_down(s, off, 64);
    if ((tid & 63) == 0) red[tid >> 6] = s;
    __syncthreads();
    if (tid == 0) {
        float t = 0.f;
#pragma unroll
        for (int i = 0; i < 16; ++i) t += red[i];
        out[OUT_ENT] = -t;
    }
    __syncthreads();
    float m = 0.f;
    for (int i = tid; i < NROW; i += 1024) m += maxsim[i];
#pragma unroll
    for (int off = 32; off > 0; off >>= 1) m += __shfl_down(m, off, 64);
    if ((tid & 63) == 0) red[tid >> 6] = m;
    __syncthreads();
    if (tid == 0) {
        float t = 0.f;
#pragma unroll
        for (int i = 0; i < 16; ++i) t += red[i];
        out[OUT_MEAN] = t * (1.0f / 16384.0f);
    }
}

extern "C" void kernel_launch(void* const* d_in, const int* in_sizes, int n_in,
                              void* d_out, int out_size, void* d_ws, size_t ws_size,
                              hipStream_t stream) {
    const float* x  = (const float*)d_in[0];
    const float* cb = (const float*)d_in[1];
    float* out = (float*)d_out;
    float* wsf = (float*)d_ws;
    int*   wsi = (int*)d_ws;

    float* xnorm   = wsf + WS_XNORM;
    float* xrcp    = wsf + WS_XRCP;
    float* cbnorm  = wsf + WS_CBNORM;
    float* cbrcp   = wsf + WS_CBRCP;
    float* candval = wsf + WS_CANDV;
    int*   candidx = wsi + WS_CANDI;
    float* maxsim  = wsf + WS_MAXSIM;
    int*   counts  = wsi + WS_COUNTS;

    hipMemsetAsync(counts, 0, VOCAB * sizeof(int), stream);

    eq_rownorm<<<NROW, 64, 0, stream>>>(x, xnorm, xrcp, NROW);
    eq_rownorm<<<VOCAB, 64, 0, stream>>>(cb, cbnorm, cbrcp, VOCAB);

    eq_gemm_top2<<<dim3(NROW / BM, VSPLIT), NT, 0, stream>>>(
        x, cb, cbrcp, candval, candidx);

    eq_finalize<<<NROW / 4, 256, 0, stream>>>(
        x, cb, xnorm, cbnorm, candidx, out, maxsim, counts);

    eq_entropy_mean<<<1, 1024, 0, stream>>>(counts, maxsim, out);
}

// Round 2
// 929.998 us; speedup vs baseline: 2.0037x; 2.0037x over previous
//
#include <hip/hip_runtime.h>

typedef short bf16x8 __attribute__((ext_vector_type(8)));
typedef float f32x4  __attribute__((ext_vector_type(4)));

#define NROW  16384
#define DD    512
#define VOCAB 8192
#define VS    4
#define VCH   (VOCAB / VS)   // 2048 vocab per split
#define BM    128            // vocab chunk
#define BN    128            // x rows per block
#define BK    64
#define NCHUNK (VCH / BM)    // 16
#define NKT    (DD / BK)     // 8
#define NLIST  (VS * 2)      // 8 candidate lists per row

// ---- out-buffer layout (float words); all overwritten by final z_q/idx ----
#define XBF_W    0                       // x as bf16: 16384*512*2B = 4,194,304 words
#define CBBF_W   4194304                 // cb normalized bf16: 2,097,152 words
#define CANDV_W  6291456                 // [8][16384][2] float
#define CANDI_W  6815744                 // [8][16384][2] int
#define OUT_IDX  ((size_t)NROW * DD)     // 8388608
#define OUT_ENT  (OUT_IDX + NROW)
#define OUT_MEAN (OUT_ENT + 1)

// ---- ws layout (words) ----
#define WS_CBNORM 0
#define WS_CBRCP  8192
#define WS_MAXSIM 16384
#define WS_COUNTS 32768

__device__ __forceinline__ ushort f2bf(float f) {
    unsigned u = __float_as_uint(f);
    return (ushort)((u + 0x7fffu + ((u >> 16) & 1u)) >> 16);   // RNE
}

// ---------------- codebook row L2 norms (one wave per row) ----------------
__global__ void eq_rownorm(const float* __restrict__ src, float* __restrict__ nrm,
                           float* __restrict__ rcp) {
    int row = blockIdx.x;
    int l = threadIdx.x;
    const float* p = src + (size_t)row * DD;
    float s = 0.f;
#pragma unroll
    for (int i = 0; i < 2; ++i) {
        float4 v = *(const float4*)(p + i * 256 + l * 4);
        s += v.x * v.x + v.y * v.y + v.z * v.z + v.w * v.w;
    }
#pragma unroll
    for (int off = 32; off > 0; off >>= 1) s += __shfl_down(s, off, 64);
    if (l == 0) {
        float n = fmaxf(sqrtf(s), 1e-12f);
        nrm[row] = n;
        rcp[row] = 1.0f / n;
    }
}

// ---------------- fp32 -> bf16 conversions ----------------
__global__ void eq_convx(const float* __restrict__ src, ushort* __restrict__ dst) {
    size_t i = ((size_t)blockIdx.x * 256 + threadIdx.x) * 8;
    float4 v0 = *(const float4*)(src + i);
    float4 v1 = *(const float4*)(src + i + 4);
    ushort r[8] = {f2bf(v0.x), f2bf(v0.y), f2bf(v0.z), f2bf(v0.w),
                   f2bf(v1.x), f2bf(v1.y), f2bf(v1.z), f2bf(v1.w)};
    *(uint4*)(dst + i) = *(const uint4*)r;
}

__global__ void eq_convcb(const float* __restrict__ src, const float* __restrict__ rcp,
                          ushort* __restrict__ dst) {
    size_t i = ((size_t)blockIdx.x * 256 + threadIdx.x) * 8;
    int row = (int)(i >> 9);
    float rn = rcp[row];
    float4 v0 = *(const float4*)(src + i);
    float4 v1 = *(const float4*)(src + i + 4);
    ushort r[8] = {f2bf(v0.x * rn), f2bf(v0.y * rn), f2bf(v0.z * rn), f2bf(v0.w * rn),
                   f2bf(v1.x * rn), f2bf(v1.y * rn), f2bf(v1.z * rn), f2bf(v1.w * rn)};
    *(uint4*)(dst + i) = *(const uint4*)r;
}

// ---------------- MFMA candidate pass ----------------
// Transposed: A = cb (M=vocab), B = x (N=rows). C[row=vocab][col=xrow],
// col = lane&15 -> each lane owns 4 x-rows, sees 16 vocab values per chunk.
// Per-lane running top-2 across the split scan; 2-step butterfly merge at end.
__global__ __launch_bounds__(256, 2) void eq_gemm_topk(
    const ushort* __restrict__ xbf, const ushort* __restrict__ cbbf,
    float* __restrict__ candval, int* __restrict__ candidx) {
    __shared__ __align__(16) char Asm[BM * BK * 2];   // 16 KB, XOR-swizzled
    __shared__ __align__(16) char Bsm[BN * BK * 2];   // 16 KB
    const int tid = threadIdx.x;
    const int lane = tid & 63;
    const int w = tid >> 6;
    const int wm = w >> 1, wn = w & 1;
    const int c = lane & 15, q = lane >> 4;
    const int xbase = blockIdx.x * BN;
    const int vsplit = blockIdx.y;
    const int vsbase = vsplit * VCH;

    // staging assignment: 4 x (row, 8-elem segment) per thread
    int srow[4], skoff[4], swaddr[4];
#pragma unroll
    for (int p = 0; p < 4; ++p) {
        int id = tid + p * 256;
        int r = id >> 3, seg = id & 7;
        srow[p] = r;
        skoff[p] = seg * 8;
        swaddr[p] = r * 128 + ((seg * 16) ^ ((r & 7) << 4));
    }

    uint4 va[4], vb[4];
    // prefetch tile (ch=0, kt=0)
#pragma unroll
    for (int p = 0; p < 4; ++p) {
        va[p] = *(const uint4*)(cbbf + (size_t)(vsbase + srow[p]) * DD + skoff[p]);
        vb[p] = *(const uint4*)(xbf  + (size_t)(xbase  + srow[p]) * DD + skoff[p]);
    }

    float t1v[4], t2v[4];
    int   t1i[4], t2i[4];
#pragma unroll
    for (int nj = 0; nj < 4; ++nj) {
        t1v[nj] = -3.0e38f; t2v[nj] = -3.0e38f;
        t1i[nj] = 1 << 30;  t2i[nj] = 1 << 30;
    }

    const int sw = (c & 7) << 4;

    for (int ch = 0; ch < NCHUNK; ++ch) {
        f32x4 acc[4][4];
#pragma unroll
        for (int mi = 0; mi < 4; ++mi)
#pragma unroll
            for (int nj = 0; nj < 4; ++nj) acc[mi][nj] = (f32x4){0.f, 0.f, 0.f, 0.f};

        for (int kt = 0; kt < NKT; ++kt) {
            __syncthreads();   // previous tile's readers done
#pragma unroll
            for (int p = 0; p < 4; ++p) {
                *(uint4*)(Asm + swaddr[p]) = va[p];
                *(uint4*)(Bsm + swaddr[p]) = vb[p];
            }
            int lin = ch * NKT + kt + 1;
            if (lin < NCHUNK * NKT) {
                int nch = lin >> 3, nkt = lin & 7;
#pragma unroll
                for (int p = 0; p < 4; ++p) {
                    va[p] = *(const uint4*)(cbbf + (size_t)(vsbase + nch * BM + srow[p]) * DD + nkt * BK + skoff[p]);
                    vb[p] = *(const uint4*)(xbf  + (size_t)(xbase + srow[p]) * DD + nkt * BK + skoff[p]);
                }
            }
            __syncthreads();
#pragma unroll
            for (int s = 0; s < 2; ++s) {
                const int kb = s * 64 + q * 16;
                bf16x8 af[4], bfr[4];
#pragma unroll
                for (int mi = 0; mi < 4; ++mi)
                    af[mi] = *(const bf16x8*)(Asm + (wm * 64 + mi * 16 + c) * 128 + (kb ^ sw));
#pragma unroll
                for (int nj = 0; nj < 4; ++nj)
                    bfr[nj] = *(const bf16x8*)(Bsm + (wn * 64 + nj * 16 + c) * 128 + (kb ^ sw));
#pragma unroll
                for (int mi = 0; mi < 4; ++mi)
#pragma unroll
                    for (int nj = 0; nj < 4; ++nj)
                        acc[mi][nj] = __builtin_amdgcn_mfma_f32_16x16x32_bf16(
                            af[mi], bfr[nj], acc[mi][nj], 0, 0, 0);
            }
        }
        // fold chunk into per-lane top-2 (vocab ascending -> strict > keeps smallest idx)
        const int base_ch = vsbase + ch * BM + wm * 64 + q * 4;
#pragma unroll
        for (int nj = 0; nj < 4; ++nj) {
#pragma unroll
            for (int mi = 0; mi < 4; ++mi) {
#pragma unroll
                for (int r = 0; r < 4; ++r) {
                    float v = acc[mi][nj][r];
                    int idx = base_ch + mi * 16 + r;
                    bool b1 = v > t1v[nj];
                    bool b2 = v > t2v[nj];
                    t2v[nj] = b1 ? t1v[nj] : (b2 ? v : t2v[nj]);
                    t2i[nj] = b1 ? t1i[nj] : (b2 ? idx : t2i[nj]);
                    t1v[nj] = b1 ? v : t1v[nj];
                    t1i[nj] = b1 ? idx : t1i[nj];
                }
            }
        }
    }
    // merge the 4 disjoint q-lanes (xor 16, xor 32): exact noisy top-2 of the list
#pragma unroll
    for (int off = 16; off <= 32; off <<= 1) {
#pragma unroll
        for (int nj = 0; nj < 4; ++nj) {
            float o1v = __shfl_xor(t1v[nj], off, 64); int o1i = __shfl_xor(t1i[nj], off, 64);
            float o2v = __shfl_xor(t2v[nj], off, 64); int o2i = __shfl_xor(t2i[nj], off, 64);
            bool wbest = (t1v[nj] > o1v) || (t1v[nj] == o1v && t1i[nj] < o1i);
            float m1 = wbest ? t1v[nj] : o1v;  int m1i = wbest ? t1i[nj] : o1i;
            float ca = wbest ? o1v : t1v[nj];  int cai = wbest ? o1i : t1i[nj];
            float cw = wbest ? t2v[nj] : o2v;  int cwi = wbest ? t2i[nj] : o2i;
            bool s2 = (ca > cw) || (ca == cw && cai < cwi);
            t1v[nj] = m1;            t1i[nj] = m1i;
            t2v[nj] = s2 ? ca : cw;  t2i[nj] = s2 ? cai : cwi;
        }
    }
    if (q == 0) {
        int list = vsplit * 2 + wm;
#pragma unroll
        for (int nj = 0; nj < 4; ++nj) {
            int row = xbase + wn * 64 + nj * 16 + c;
            size_t base = ((size_t)list * NROW + row) * 2;
            candval[base] = t1v[nj]; candval[base + 1] = t2v[nj];
            candidx[base] = t1i[nj]; candidx[base + 1] = t2i[nj];
        }
    }
}

// ---------------- fp64 rescore of 16 candidates; idx + maxsim + histogram ----------------
__global__ void eq_rescore(const float* __restrict__ x, const float* __restrict__ cb,
                           const float* __restrict__ cbnorm, const int* __restrict__ candidx,
                           float* __restrict__ out, float* __restrict__ maxsim,
                           int* __restrict__ counts) {
    int w = threadIdx.x >> 6, l = threadIdx.x & 63;
    int row = blockIdx.x * 4 + w;

    float xe[8];
    float s2 = 0.f;
#pragma unroll
    for (int p = 0; p < 8; ++p) {
        xe[p] = x[(size_t)row * DD + p * 64 + l];
        s2 += xe[p] * xe[p];
    }
#pragma unroll
    for (int off = 32; off > 0; off >>= 1) s2 += __shfl_xor(s2, off, 64);
    float xn = fmaxf(sqrtf(s2), 1e-12f);

    int cidx[16]; float cbn[16];
#pragma unroll
    for (int t = 0; t < 16; ++t)
        cidx[t] = candidx[((size_t)(t >> 1) * NROW + row) * 2 + (t & 1)];
#pragma unroll
    for (int t = 0; t < 16; ++t) cbn[t] = cbnorm[cidx[t]];

    double acc[16];
#pragma unroll
    for (int t = 0; t < 16; ++t) acc[t] = 0.0;
#pragma unroll
    for (int p = 0; p < 8; ++p) {
        int e = p * 64 + l;
        double xd = (double)(xe[p] / xn);        // exact fp32 rounding as reference
#pragma unroll
        for (int t = 0; t < 16; ++t) {
            float ce = cb[(size_t)cidx[t] * DD + e] / cbn[t];
            acc[t] += xd * (double)ce;
        }
    }
#pragma unroll
    for (int off = 32; off > 0; off >>= 1)
#pragma unroll
        for (int t = 0; t < 16; ++t) acc[t] += __shfl_xor(acc[t], off, 64);

    if (l == 0) {
        double bv = -1.0e30; int bi = 1 << 30;
#pragma unroll
        for (int t = 0; t < 16; ++t) {
            bool better = (acc[t] > bv) || (acc[t] == bv && cidx[t] < bi);
            bv = better ? acc[t] : bv;
            bi = better ? cidx[t] : bi;
        }
        out[OUT_IDX + row] = (float)bi;
        maxsim[row] = (float)bv;
        atomicAdd(counts + bi, 1);
    }
}

// ---------------- z_q gather (after rescore; overwrites scratch regions) ----------------
__global__ void eq_gather(const float* __restrict__ cb, float* __restrict__ out) {
    int w = threadIdx.x >> 6, l = threadIdx.x & 63;
    int row = blockIdx.x * 4 + w;
    int bi = (int)out[OUT_IDX + row];
    const float4* src = (const float4*)(cb + (size_t)bi * DD);
    float4* dst = (float4*)(out + (size_t)row * DD);
    dst[l] = src[l];
    dst[l + 64] = src[l + 64];
}

// ---------------- entropy + mean ----------------
__global__ void eq_entropy_mean(const int* __restrict__ counts,
                                const float* __restrict__ maxsim,
                                float* __restrict__ out) {
    __shared__ float red[16];
    int tid = threadIdx.x;   // 1024
    float s = 0.f;
    for (int b = tid; b < VOCAB; b += 1024) {
        int c = counts[b];
        if (c > 0) {
            float p = (float)c * (1.0f / 16384.0f);
            s += p * logf(p);
        }
    }
#pragma unroll
    for (int off = 32; off > 0; off >>= 1) s += __shfl_down(s, off, 64);
    if ((tid & 63) == 0) red[tid >> 6] = s;
    __syncthreads();
    if (tid == 0) {
        float t = 0.f;
#pragma unroll
        for (int i = 0; i < 16; ++i) t += red[i];
        out[OUT_ENT] = -t;
    }
    __syncthreads();
    float m = 0.f;
    for (int i = tid; i < NROW; i += 1024) m += maxsim[i];
#pragma unroll
    for (int off = 32; off > 0; off >>= 1) m += __shfl_down(m, off, 64);
    if ((tid & 63) == 0) red[tid >> 6] = m;
    __syncthreads();
    if (tid == 0) {
        float t = 0.f;
#pragma unroll
        for (int i = 0; i < 16; ++i) t += red[i];
        out[OUT_MEAN] = t * (1.0f / 16384.0f);
    }
}

extern "C" void kernel_launch(void* const* d_in, const int* in_sizes, int n_in,
                              void* d_out, int out_size, void* d_ws, size_t ws_size,
                              hipStream_t stream) {
    const float* x  = (const float*)d_in[0];
    const float* cb = (const float*)d_in[1];
    float* out = (float*)d_out;
    float* wsf = (float*)d_ws;
    int*   wsi = (int*)d_ws;

    float* cbnorm = wsf + WS_CBNORM;
    float* cbrcp  = wsf + WS_CBRCP;
    float* maxsim = wsf + WS_MAXSIM;
    int*   counts = wsi + WS_COUNTS;

    ushort* xbf  = (ushort*)out;                 // scratch in out, overwritten by z_q
    ushort* cbbf = (ushort*)(out + CBBF_W);
    float*  candv = out + CANDV_W;
    int*    candi = (int*)(out + CANDI_W);

    hipMemsetAsync(counts, 0, VOCAB * sizeof(int), stream);

    eq_rownorm<<<VOCAB, 64, 0, stream>>>(cb, cbnorm, cbrcp);
    eq_convx<<<4096, 256, 0, stream>>>(x, xbf);
    eq_convcb<<<2048, 256, 0, stream>>>(cb, cbrcp, cbbf);

    eq_gemm_topk<<<dim3(NROW / BN, VS), 256, 0, stream>>>(xbf, cbbf, candv, candi);

    eq_rescore<<<NROW / 4, 256, 0, stream>>>(x, cb, cbnorm, candi, out, maxsim, counts);
    eq_gather<<<NROW / 4, 256, 0, stream>>>(cb, out);
    eq_entropy_mean<<<1, 1024, 0, stream>>>(counts, maxsim, out);
}

// Round 3
// 346.877 us; speedup vs baseline: 5.3722x; 2.6811x over previous
//
#include <hip/hip_runtime.h>

typedef short bf16x8 __attribute__((ext_vector_type(8)));
typedef float f32x4  __attribute__((ext_vector_type(4)));

#define NROW  16384
#define DD    512
#define VOCAB 8192
#define VS    4
#define VCH   2048           // vocab rows per split
#define BM    128            // vocab tile
#define BN    128            // x-row tile
#define BK    64
#define NCHUNK 16            // VCH/BM
#define NKT    8             // DD/BK
#define NTILE  128           // NCHUNK*NKT

// ---- out-buffer scratch layout (float words); all overwritten by final z_q ----
// xbf   words 0..4194304        (x bf16)   -> later reused for cb_norm fp32
// cbbf  words 4194304..6291456  (cb normalized bf16)
// candv words 6291456..6553600  [8][16384][2] float
// candi words 6815744..7077888  [8][16384][2] int
#define CBBF_W   4194304
#define CANDV_W  6291456
#define CANDI_W  6815744
#define OUT_IDX  ((size_t)NROW * DD)
#define OUT_ENT  (OUT_IDX + NROW)
#define OUT_MEAN (OUT_ENT + 1)

// ---- ws layout (words) ----
#define WS_CBNORM 0
#define WS_CBRCP  8192
#define WS_MAXSIM 16384
#define WS_COUNTS 32768

#define GLD_LDS(g, l) \
    __builtin_amdgcn_global_load_lds((const __attribute__((address_space(1))) void*)(g), \
                                     (__attribute__((address_space(3))) void*)(l), 16, 0, 0)

__device__ __forceinline__ ushort f2bf(float f) {
    unsigned u = __float_as_uint(f);
    return (ushort)((u + 0x7fffu + ((u >> 16) & 1u)) >> 16);   // RNE
}

// ---------------- codebook row L2 norms (one wave per row) ----------------
__global__ void eq_rownorm(const float* __restrict__ src, float* __restrict__ nrm,
                           float* __restrict__ rcp) {
    int row = blockIdx.x;
    int l = threadIdx.x;
    const float* p = src + (size_t)row * DD;
    float s = 0.f;
#pragma unroll
    for (int i = 0; i < 2; ++i) {
        float4 v = *(const float4*)(p + i * 256 + l * 4);
        s += v.x * v.x + v.y * v.y + v.z * v.z + v.w * v.w;
    }
#pragma unroll
    for (int off = 32; off > 0; off >>= 1) s += __shfl_down(s, off, 64);
    if (l == 0) {
        float n = fmaxf(sqrtf(s), 1e-12f);
        nrm[row] = n;
        rcp[row] = 1.0f / n;
    }
}

// ---------------- fp32 -> bf16 conversions ----------------
__global__ void eq_convx(const float* __restrict__ src, ushort* __restrict__ dst) {
    size_t i = ((size_t)blockIdx.x * 256 + threadIdx.x) * 8;
    float4 v0 = *(const float4*)(src + i);
    float4 v1 = *(const float4*)(src + i + 4);
    ushort r[8] = {f2bf(v0.x), f2bf(v0.y), f2bf(v0.z), f2bf(v0.w),
                   f2bf(v1.x), f2bf(v1.y), f2bf(v1.z), f2bf(v1.w)};
    *(uint4*)(dst + i) = *(const uint4*)r;
}

__global__ void eq_convcb(const float* __restrict__ src, const float* __restrict__ rcp,
                          ushort* __restrict__ dst) {
    size_t i = ((size_t)blockIdx.x * 256 + threadIdx.x) * 8;
    int row = (int)(i >> 9);
    float rn = rcp[row];
    float4 v0 = *(const float4*)(src + i);
    float4 v1 = *(const float4*)(src + i + 4);
    ushort r[8] = {f2bf(v0.x * rn), f2bf(v0.y * rn), f2bf(v0.z * rn), f2bf(v0.w * rn),
                   f2bf(v1.x * rn), f2bf(v1.y * rn), f2bf(v1.z * rn), f2bf(v1.w * rn)};
    *(uint4*)(dst + i) = *(const uint4*)r;
}

// ---------------- exact fp32 normalized codebook (for rescore) ----------------
__global__ void eq_normcb(const float* __restrict__ cb, const float* __restrict__ nrm,
                          float* __restrict__ dst) {
    size_t i = ((size_t)blockIdx.x * 256 + threadIdx.x) * 4;
    int row = (int)(i >> 9);
    float n = nrm[row];
    float4 v = *(const float4*)(cb + i);
    float4 r = {v.x / n, v.y / n, v.z / n, v.w / n};   // exact fp32 div as reference
    *(float4*)(dst + i) = r;
}

// ---------------- MFMA candidate pass (m97 structure: gload_lds + dbuf) ----------------
// Transposed MFMA: A = cb (M=vocab), B = x (N=xrows). Lane-local top-2 per
// (vsplit, wm) 1024-entry vocab list; 2-step butterfly merge at end.
__global__ __launch_bounds__(256, 2) void eq_gemm_topk(
    const ushort* __restrict__ xbf, const ushort* __restrict__ cbbf,
    float* __restrict__ candval, int* __restrict__ candidx) {
    __shared__ __align__(16) char As[2][BM * BK * 2];   // 16 KB x2
    __shared__ __align__(16) char Bs[2][BN * BK * 2];   // 16 KB x2
    const int tid = threadIdx.x;
    const int lane = tid & 63;
    const int w = tid >> 6;
    const int wm = w >> 1, wn = w & 1;
    const int c = lane & 15, q = lane >> 4;

    // bijective XCD swizzle: 512 blocks, 64 per XCD, same vsplit per XCD
    int bid = blockIdx.x + gridDim.x * blockIdx.y;       // 0..511
    int sid = (bid & 7) * 64 + (bid >> 3);
    const int xbase = (sid & 127) * BN;
    const int vsplit = sid >> 7;
    const int vsbase = vsplit * VCH;

    const char* gx  = (const char*)xbf  + (size_t)xbase  * (DD * 2);
    const char* gcb = (const char*)cbbf + (size_t)vsbase * (DD * 2);
    // pre-swizzled per-lane source offset: row-within-8 = lane>>3, seg = (lane&7)^(lane>>3)
    const int po = ((lane >> 3) << 10) | ((((lane & 7) ^ (lane >> 3)) << 4));
    const int woff = w * 32768;          // wave covers 32 rows (32 KB of global)
    const int sw = (c & 7) << 4;         // read-side XOR swizzle

    float t1v[4], t2v[4]; int t1i[4], t2i[4];
#pragma unroll
    for (int nj = 0; nj < 4; ++nj) {
        t1v[nj] = -3.0e38f; t2v[nj] = -3.0e38f;
        t1i[nj] = 1 << 30;  t2i[nj] = 1 << 30;
    }

    // prologue: stage tile 0 -> buf 0
#pragma unroll
    for (int i = 0; i < 4; ++i) {
        GLD_LDS(gcb + woff + i * 8192 + po, &As[0][w * 4096 + i * 1024]);
        GLD_LDS(gx  + woff + i * 8192 + po, &Bs[0][w * 4096 + i * 1024]);
    }
    __syncthreads();

    int cur = 0;
    for (int ch = 0; ch < NCHUNK; ++ch) {
        f32x4 acc[4][4];
#pragma unroll
        for (int mi = 0; mi < 4; ++mi)
#pragma unroll
            for (int nj = 0; nj < 4; ++nj) acc[mi][nj] = (f32x4){0.f, 0.f, 0.f, 0.f};

        for (int kt = 0; kt < NKT; ++kt) {
            // issue next tile's loads into the other buffer (overlap with MFMA)
            int lin = ch * NKT + kt + 1;
            if (lin < NTILE) {
                int nch = lin >> 3, nkt = lin & 7;
                const char* ga = gcb + (size_t)nch * 131072 + nkt * 128 + woff + po;
                const char* gb = gx  + nkt * 128 + woff + po;
#pragma unroll
                for (int i = 0; i < 4; ++i) {
                    GLD_LDS(ga + i * 8192, &As[cur ^ 1][w * 4096 + i * 1024]);
                    GLD_LDS(gb + i * 8192, &Bs[cur ^ 1][w * 4096 + i * 1024]);
                }
            }
            // compute current buffer
#pragma unroll
            for (int s = 0; s < 2; ++s) {
                const int kb = (s * 64 + q * 16) ^ sw;
                bf16x8 af[4], bfr[4];
#pragma unroll
                for (int mi = 0; mi < 4; ++mi)
                    af[mi] = *(const bf16x8*)(&As[cur][(wm * 64 + mi * 16 + c) * 128 + kb]);
#pragma unroll
                for (int nj = 0; nj < 4; ++nj)
                    bfr[nj] = *(const bf16x8*)(&Bs[cur][(wn * 64 + nj * 16 + c) * 128 + kb]);
#pragma unroll
                for (int mi = 0; mi < 4; ++mi)
#pragma unroll
                    for (int nj = 0; nj < 4; ++nj)
                        acc[mi][nj] = __builtin_amdgcn_mfma_f32_16x16x32_bf16(
                            af[mi], bfr[nj], acc[mi][nj], 0, 0, 0);
            }
            __syncthreads();     // drains vmcnt(0): next buffer staged; readers done
            cur ^= 1;
        }
        // fold chunk into per-lane top-2 (vocab ascending -> strict > keeps smallest idx)
        const int base_ch = vsbase + ch * BM + wm * 64 + q * 4;
#pragma unroll
        for (int nj = 0; nj < 4; ++nj)
#pragma unroll
            for (int mi = 0; mi < 4; ++mi)
#pragma unroll
                for (int r = 0; r < 4; ++r) {
                    float v = acc[mi][nj][r];
                    int idx = base_ch + mi * 16 + r;
                    bool b1 = v > t1v[nj];
                    bool b2 = v > t2v[nj];
                    t2v[nj] = b1 ? t1v[nj] : (b2 ? v : t2v[nj]);
                    t2i[nj] = b1 ? t1i[nj] : (b2 ? idx : t2i[nj]);
                    t1v[nj] = b1 ? v : t1v[nj];
                    t1i[nj] = b1 ? idx : t1i[nj];
                }
    }
    // merge the 4 disjoint q-lanes (xor 16, xor 32)
#pragma unroll
    for (int off = 16; off <= 32; off <<= 1) {
#pragma unroll
        for (int nj = 0; nj < 4; ++nj) {
            float o1v = __shfl_xor(t1v[nj], off, 64); int o1i = __shfl_xor(t1i[nj], off, 64);
            float o2v = __shfl_xor(t2v[nj], off, 64); int o2i = __shfl_xor(t2i[nj], off, 64);
            bool wbest = (t1v[nj] > o1v) || (t1v[nj] == o1v && t1i[nj] < o1i);
            float m1 = wbest ? t1v[nj] : o1v;  int m1i = wbest ? t1i[nj] : o1i;
            float ca = wbest ? o1v : t1v[nj];  int cai = wbest ? o1i : t1i[nj];
            float cw = wbest ? t2v[nj] : o2v;  int cwi = wbest ? t2i[nj] : o2i;
            bool s2 = (ca > cw) || (ca == cw && cai < cwi);
            t1v[nj] = m1;            t1i[nj] = m1i;
            t2v[nj] = s2 ? ca : cw;  t2i[nj] = s2 ? cai : cwi;
        }
    }
    if (q == 0) {
        int list = vsplit * 2 + wm;
#pragma unroll
        for (int nj = 0; nj < 4; ++nj) {
            int row = xbase + wn * 64 + nj * 16 + c;
            size_t base = ((size_t)list * NROW + row) * 2;
            candval[base] = t1v[nj]; candval[base + 1] = t2v[nj];
            candidx[base] = t1i[nj]; candidx[base + 1] = t2i[nj];
        }
    }
}

// ---------------- fp64 rescore with margin prefilter ----------------
__global__ void eq_rescore(const float* __restrict__ x, const float* __restrict__ cbn,
                           const float* __restrict__ candval, const int* __restrict__ candidx,
                           float* __restrict__ out, float* __restrict__ maxsim,
                           int* __restrict__ counts) {
    int w = threadIdx.x >> 6, l = threadIdx.x & 63;
    int row = blockIdx.x * 4 + w;

    const float4* X4 = (const float4*)(x + (size_t)row * DD);
    float4 xa = X4[l], xb = X4[l + 64];
    float s2 = xa.x * xa.x + xa.y * xa.y + xa.z * xa.z + xa.w * xa.w
             + xb.x * xb.x + xb.y * xb.y + xb.z * xb.z + xb.w * xb.w;
#pragma unroll
    for (int off = 32; off > 0; off >>= 1) s2 += __shfl_xor(s2, off, 64);
    float xn = fmaxf(sqrtf(s2), 1e-12f);
    double xd[8] = {(double)(xa.x / xn), (double)(xa.y / xn), (double)(xa.z / xn),
                    (double)(xa.w / xn), (double)(xb.x / xn), (double)(xb.y / xn),
                    (double)(xb.z / xn), (double)(xb.w / xn)};

    float cv[16]; int ci[16];
#pragma unroll
    for (int t = 0; t < 16; ++t) {
        size_t b = ((size_t)(t >> 1) * NROW + row) * 2 + (t & 1);
        cv[t] = candval[b]; ci[t] = candidx[b];
    }
    float bv1 = cv[0];
#pragma unroll
    for (int t = 1; t < 16; ++t) bv1 = fmaxf(bv1, cv[t]);
    // candval scale is ||x||*sim; bf16-GEMM noise ~7e-5*||x|| -> margin = 28 sigma
    float margin = 2e-3f * xn;

    double best = -1e300; int bi = 1 << 30;
    for (int t = 0; t < 16; ++t) {
        if (cv[t] >= bv1 - margin) {                 // wave-uniform branch
            const float4* C4 = (const float4*)(cbn + (size_t)ci[t] * DD);
            float4 ca = C4[l], cb4 = C4[l + 64];
            double a = xd[0] * (double)ca.x + xd[1] * (double)ca.y
                     + xd[2] * (double)ca.z + xd[3] * (double)ca.w
                     + xd[4] * (double)cb4.x + xd[5] * (double)cb4.y
                     + xd[6] * (double)cb4.z + xd[7] * (double)cb4.w;
#pragma unroll
            for (int off = 32; off > 0; off >>= 1) a += __shfl_xor(a, off, 64);
            bool better = (a > best) || (a == best && ci[t] < bi);
            best = better ? a : best;
            bi = better ? ci[t] : bi;
        }
    }
    if (l == 0) {
        out[OUT_IDX + row] = (float)bi;
        maxsim[row] = (float)best;
        atomicAdd(counts + bi, 1);
    }
}

// ---------------- z_q gather ----------------
__global__ void eq_gather(const float* __restrict__ cb, float* __restrict__ out) {
    int w = threadIdx.x >> 6, l = threadIdx.x & 63;
    int row = blockIdx.x * 4 + w;
    int bi = (int)out[OUT_IDX + row];
    const float4* src = (const float4*)(cb + (size_t)bi * DD);
    float4* dst = (float4*)(out + (size_t)row * DD);
    dst[l] = src[l];
    dst[l + 64] = src[l + 64];
}

// ---------------- entropy + mean ----------------
__global__ void eq_entropy_mean(const int* __restrict__ counts,
                                const float* __restrict__ maxsim,
                                float* __restrict__ out) {
    __shared__ float red[16];
    int tid = threadIdx.x;   // 1024
    float s = 0.f;
    for (int b = tid; b < VOCAB; b += 1024) {
        int c = counts[b];
        if (c > 0) {
            float p = (float)c * (1.0f / 16384.0f);
            s += p * logf(p);
        }
    }
#pragma unroll
    for (int off = 32; off > 0; off >>= 1) s += __shfl_down(s, off, 64);
    if ((tid & 63) == 0) red[tid >> 6] = s;
    __syncthreads();
    if (tid == 0) {
        float t = 0.f;
#pragma unroll
        for (int i = 0; i < 16; ++i) t += red[i];
        out[OUT_ENT] = -t;
    }
    __syncthreads();
    float m = 0.f;
    for (int i = tid; i < NROW; i += 1024) m += maxsim[i];
#pragma unroll
    for (int off = 32; off > 0; off >>= 1) m += __shfl_down(m, off, 64);
    if ((tid & 63) == 0) red[tid >> 6] = m;
    __syncthreads();
    if (tid == 0) {
        float t = 0.f;
#pragma unroll
        for (int i = 0; i < 16; ++i) t += red[i];
        out[OUT_MEAN] = t * (1.0f / 16384.0f);
    }
}

extern "C" void kernel_launch(void* const* d_in, const int* in_sizes, int n_in,
                              void* d_out, int out_size, void* d_ws, size_t ws_size,
                              hipStream_t stream) {
    const float* x  = (const float*)d_in[0];
    const float* cb = (const float*)d_in[1];
    float* out = (float*)d_out;
    float* wsf = (float*)d_ws;
    int*   wsi = (int*)d_ws;

    float* cbnorm = wsf + WS_CBNORM;
    float* cbrcp  = wsf + WS_CBRCP;
    float* maxsim = wsf + WS_MAXSIM;
    int*   counts = wsi + WS_COUNTS;

    ushort* xbf   = (ushort*)out;                 // scratch in out
    ushort* cbbf  = (ushort*)(out + CBBF_W);
    float*  candv = out + CANDV_W;
    int*    candi = (int*)(out + CANDI_W);
    float*  cbn32 = out;                          // reuses dead xbf region after GEMM

    hipMemsetAsync(counts, 0, VOCAB * sizeof(int), stream);

    eq_rownorm<<<VOCAB, 64, 0, stream>>>(cb, cbnorm, cbrcp);
    eq_convx<<<4096, 256, 0, stream>>>(x, xbf);
    eq_convcb<<<2048, 256, 0, stream>>>(cb, cbrcp, cbbf);

    eq_gemm_topk<<<dim3(128, VS), 256, 0, stream>>>(xbf, cbbf, candv, candi);

    eq_normcb<<<4096, 256, 0, stream>>>(cb, cbnorm, (float*)cbn32);
    eq_rescore<<<NROW / 4, 256, 0, stream>>>(x, cbn32, candv, candi, out, maxsim, counts);
    eq_gather<<<NROW / 4, 256, 0, stream>>>(cb, out);
    eq_entropy_mean<<<1, 1024, 0, stream>>>(counts, maxsim, out);
}

// Round 4
// 329.969 us; speedup vs baseline: 5.6474x; 1.0512x over previous
//
#include <hip/hip_runtime.h>

typedef short bf16x8 __attribute__((ext_vector_type(8)));
typedef float f32x4  __attribute__((ext_vector_type(4)));

#define NROW  16384
#define DD    512
#define VOCAB 8192
#define VS    4
#define VCH   2048           // vocab rows per split
#define BM    256            // vocab tile
#define BN    256            // x-row tile
#define BK    64
#define NCHUNK 8             // VCH/BM
#define NKT    8             // DD/BK
#define NTILE  64            // NCHUNK*NKT

// ---- out-buffer scratch layout (float words); all overwritten by final z_q ----
#define CBBF_W   4194304                 // cb normalized bf16 after x bf16
#define CANDV_W  6291456                 // [8][16384][2] float
#define CANDI_W  6815744                 // [8][16384][2] int
#define OUT_IDX  ((size_t)NROW * DD)
#define OUT_ENT  (OUT_IDX + NROW)
#define OUT_MEAN (OUT_ENT + 1)

// ---- ws layout (words) ----
#define WS_CBNORM 0
#define WS_MAXSIM 16384
#define WS_COUNTS 32768

#define GLD_LDS(g, l) \
    __builtin_amdgcn_global_load_lds((const __attribute__((address_space(1))) void*)(g), \
                                     (__attribute__((address_space(3))) void*)(l), 16, 0, 0)

__device__ __forceinline__ ushort f2bf(float f) {
    unsigned u = __float_as_uint(f);
    return (ushort)((u + 0x7fffu + ((u >> 16) & 1u)) >> 16);   // RNE
}

// ---------------- fused: codebook norm + bf16-normalized + norm array ----------------
// one wave per cb row
__global__ void eq_prep_cb(const float* __restrict__ cb, ushort* __restrict__ cbbf,
                           float* __restrict__ nrm) {
    int row = blockIdx.x;
    int l = threadIdx.x;
    const float* p = cb + (size_t)row * DD;
    float4 a = *(const float4*)(p + l * 4);
    float4 b = *(const float4*)(p + 256 + l * 4);
    float s = a.x * a.x + a.y * a.y + a.z * a.z + a.w * a.w
            + b.x * b.x + b.y * b.y + b.z * b.z + b.w * b.w;
#pragma unroll
    for (int off = 32; off > 0; off >>= 1) s += __shfl_xor(s, off, 64);
    float n = fmaxf(sqrtf(s), 1e-12f);
    float rn = 1.0f / n;
    ushort r0[4] = {f2bf(a.x * rn), f2bf(a.y * rn), f2bf(a.z * rn), f2bf(a.w * rn)};
    ushort r1[4] = {f2bf(b.x * rn), f2bf(b.y * rn), f2bf(b.z * rn), f2bf(b.w * rn)};
    *(uint2*)(cbbf + (size_t)row * DD + l * 4)       = *(const uint2*)r0;
    *(uint2*)(cbbf + (size_t)row * DD + 256 + l * 4) = *(const uint2*)r1;
    if (l == 0) nrm[row] = n;
}

// ---------------- x fp32 -> bf16 (raw; row scale is rank-invariant) ----------------
__global__ void eq_convx(const float* __restrict__ src, ushort* __restrict__ dst) {
    size_t i = ((size_t)blockIdx.x * 256 + threadIdx.x) * 8;
    float4 v0 = *(const float4*)(src + i);
    float4 v1 = *(const float4*)(src + i + 4);
    ushort r[8] = {f2bf(v0.x), f2bf(v0.y), f2bf(v0.z), f2bf(v0.w),
                   f2bf(v1.x), f2bf(v1.y), f2bf(v1.z), f2bf(v1.w)};
    *(uint4*)(dst + i) = *(const uint4*)r;
}

// ---------------- MFMA candidate pass: 256x256x64 tiles, wave = 128x64 ----------------
// Transposed MFMA: A = cb (M=vocab), B = x (N=xrows). Packed-key top-2 per lane
// (24-bit truncated value | 8-bit local idx), exact q-merge at the end.
__global__ __launch_bounds__(512, 2) void eq_gemm_topk(
    const ushort* __restrict__ xbf, const ushort* __restrict__ cbbf,
    float* __restrict__ candval, int* __restrict__ candidx) {
    __shared__ __align__(16) char As[2][32768];   // 256 rows x 128 B, x2 dbuf
    __shared__ __align__(16) char Bs[2][32768];
    const int tid = threadIdx.x;
    const int lane = tid & 63;
    const int w = tid >> 6;          // 0..7
    const int wm = w >> 2;           // 0..1  -> 128 vocab rows
    const int wn = w & 3;            // 0..3  -> 64 x rows
    const int c = lane & 15, q = lane >> 4;

    // block mapping: XCD (bid&7 pairs) shares one vsplit's 2MB cb panel in L2
    const int bid = blockIdx.x;                  // 0..255
    const int vsplit = (bid & 7) >> 1;
    const int xtile  = ((bid >> 3) << 1) | (bid & 1);
    const int xbase  = xtile * BN;
    const int vsbase = vsplit * VCH;

    const char* ga = (const char*)cbbf + (size_t)vsbase * 1024;   // 1024 B per row
    const char* gb = (const char*)xbf  + (size_t)xbase  * 1024;
    // pre-swizzled per-lane src offset (rule #21: linear LDS dest, inverse-swz src)
    const int po = ((lane >> 3) << 10) | (((lane & 7) ^ (lane >> 3)) << 4);
    const int sw = (c & 7) << 4;     // read-side XOR swizzle

    int t1k[4], t2k[4];
#pragma unroll
    for (int nj = 0; nj < 4; ++nj) { t1k[nj] = 0x80000000; t2k[nj] = 0x80000000; }

    // prologue: stage tile 0 -> buf 0
#pragma unroll
    for (int p = 0; p < 4; ++p) {
        GLD_LDS(ga + (w * 8 + p * 64) * 1024 + po, &As[0][w * 1024 + p * 8192]);
        GLD_LDS(gb + (w * 8 + p * 64) * 1024 + po, &Bs[0][w * 1024 + p * 8192]);
    }
    __syncthreads();

    int cur = 0;
    for (int ch = 0; ch < NCHUNK; ++ch) {
        f32x4 acc[8][4];
#pragma unroll
        for (int mi = 0; mi < 8; ++mi)
#pragma unroll
            for (int nj = 0; nj < 4; ++nj) acc[mi][nj] = (f32x4){0.f, 0.f, 0.f, 0.f};

        for (int kt = 0; kt < NKT; ++kt) {
            // issue next tile's loads into the other buffer
            int lin = ch * NKT + kt + 1;
            if (lin < NTILE) {
                int nch = lin >> 3, nkt = lin & 7;
                const char* gat = ga + (size_t)nch * 262144 + nkt * 128 + po;
                const char* gbt = gb + nkt * 128 + po;
#pragma unroll
                for (int p = 0; p < 4; ++p) {
                    GLD_LDS(gat + (w * 8 + p * 64) * 1024, &As[cur ^ 1][w * 1024 + p * 8192]);
                    GLD_LDS(gbt + (w * 8 + p * 64) * 1024, &Bs[cur ^ 1][w * 1024 + p * 8192]);
                }
            }
            // compute current buffer: 2 K-sub steps x 32 MFMA
#pragma unroll
            for (int s = 0; s < 2; ++s) {
                const int kb = (s * 64 + q * 16) ^ sw;
                bf16x8 af[8], bfr[4];
#pragma unroll
                for (int mi = 0; mi < 8; ++mi)
                    af[mi] = *(const bf16x8*)(&As[cur][(wm * 128 + mi * 16 + c) * 128 + kb]);
#pragma unroll
                for (int nj = 0; nj < 4; ++nj)
                    bfr[nj] = *(const bf16x8*)(&Bs[cur][(wn * 64 + nj * 16 + c) * 128 + kb]);
#pragma unroll
                for (int mi = 0; mi < 8; ++mi)
#pragma unroll
                    for (int nj = 0; nj < 4; ++nj)
                        acc[mi][nj] = __builtin_amdgcn_mfma_f32_16x16x32_bf16(
                            af[mi], bfr[nj], acc[mi][nj], 0, 0, 0);
            }
            __syncthreads();     // drains vmcnt(0): next buffer staged; readers done
            cur ^= 1;
        }
        // packed-key top-2 fold: 5 VALU/value
        const int chb = ch << 5;
#pragma unroll
        for (int nj = 0; nj < 4; ++nj)
#pragma unroll
            for (int mi = 0; mi < 8; ++mi)
#pragma unroll
                for (int r = 0; r < 4; ++r) {
                    int key = (__float_as_int(acc[mi][nj][r]) & (int)0xFFFFFF00)
                            | (chb + mi * 4 + r);
                    int mn = t1k[nj] < key ? t1k[nj] : key;
                    t1k[nj] = t1k[nj] < key ? key : t1k[nj];
                    t2k[nj] = t2k[nj] < mn ? mn : t2k[nj];
                }
    }
    // decode keys -> (value, vocab idx), then exact merge across the 4 q-lanes
#pragma unroll
    for (int nj = 0; nj < 4; ++nj) {
        int k1 = t1k[nj], k2 = t2k[nj];
        float t1v = __int_as_float(k1 & (int)0xFFFFFF00);
        float t2v = __int_as_float(k2 & (int)0xFFFFFF00);
        int l1 = k1 & 255, l2 = k2 & 255;
        int t1i = vsbase + ((l1 >> 5) << 8) + (wm << 7) + (((l1 >> 2) & 7) << 4) + (q << 2) + (l1 & 3);
        int t2i = vsbase + ((l2 >> 5) << 8) + (wm << 7) + (((l2 >> 2) & 7) << 4) + (q << 2) + (l2 & 3);
#pragma unroll
        for (int off = 16; off <= 32; off <<= 1) {
            float o1v = __shfl_xor(t1v, off, 64); int o1i = __shfl_xor(t1i, off, 64);
            float o2v = __shfl_xor(t2v, off, 64); int o2i = __shfl_xor(t2i, off, 64);
            bool wbest = (t1v > o1v) || (t1v == o1v && t1i < o1i);
            float m1 = wbest ? t1v : o1v;  int m1i = wbest ? t1i : o1i;
            float ca = wbest ? o1v : t1v;  int cai = wbest ? o1i : t1i;
            float cw = wbest ? t2v : o2v;  int cwi = wbest ? t2i : o2i;
            bool s2 = (ca > cw) || (ca == cw && cai < cwi);
            t1v = m1;           t1i = m1i;
            t2v = s2 ? ca : cw; t2i = s2 ? cai : cwi;
        }
        if (q == 0) {
            int list = vsplit * 2 + wm;
            int row = xbase + wn * 64 + nj * 16 + c;
            size_t base = ((size_t)list * NROW + row) * 2;
            candval[base] = t1v; candval[base + 1] = t2v;
            candidx[base] = t1i; candidx[base + 1] = t2i;
        }
    }
}

// ---------------- fp64 rescore with margin prefilter (on-the-fly exact normalize) ----------------
__global__ void eq_rescore(const float* __restrict__ x, const float* __restrict__ cb,
                           const float* __restrict__ cbnorm,
                           const float* __restrict__ candval, const int* __restrict__ candidx,
                           float* __restrict__ out, float* __restrict__ maxsim,
                           int* __restrict__ counts) {
    int w = threadIdx.x >> 6, l = threadIdx.x & 63;
    int row = blockIdx.x * 4 + w;

    const float4* X4 = (const float4*)(x + (size_t)row * DD);
    float4 xa = X4[l], xb = X4[l + 64];
    float s2 = xa.x * xa.x + xa.y * xa.y + xa.z * xa.z + xa.w * xa.w
             + xb.x * xb.x + xb.y * xb.y + xb.z * xb.z + xb.w * xb.w;
#pragma unroll
    for (int off = 32; off > 0; off >>= 1) s2 += __shfl_xor(s2, off, 64);
    float xn = fmaxf(sqrtf(s2), 1e-12f);
    double xd[8] = {(double)(xa.x / xn), (double)(xa.y / xn), (double)(xa.z / xn),
                    (double)(xa.w / xn), (double)(xb.x / xn), (double)(xb.y / xn),
                    (double)(xb.z / xn), (double)(xb.w / xn)};

    float cv[16]; int ci[16];
#pragma unroll
    for (int t = 0; t < 16; ++t) {
        size_t b = ((size_t)(t >> 1) * NROW + row) * 2 + (t & 1);
        cv[t] = candval[b]; ci[t] = candidx[b];
    }
    float bv1 = cv[0];
#pragma unroll
    for (int t = 1; t < 16; ++t) bv1 = fmaxf(bv1, cv[t]);
    // candval scale is ||x||*sim; bf16 noise ~1e-4*||x|| + 3e-5 key trunc -> 2e-3 covers
    float margin = 2e-3f * xn;

    double best = -1e300; int bi = 1 << 30;
    for (int t = 0; t < 16; ++t) {
        if (cv[t] >= bv1 - margin) {                 // wave-uniform branch
            float n = cbnorm[ci[t]];
            const float4* C4 = (const float4*)(cb + (size_t)ci[t] * DD);
            float4 ca = C4[l], cb4 = C4[l + 64];
            double a = xd[0] * (double)(ca.x / n) + xd[1] * (double)(ca.y / n)
                     + xd[2] * (double)(ca.z / n) + xd[3] * (double)(ca.w / n)
                     + xd[4] * (double)(cb4.x / n) + xd[5] * (double)(cb4.y / n)
                     + xd[6] * (double)(cb4.z / n) + xd[7] * (double)(cb4.w / n);
#pragma unroll
            for (int off = 32; off > 0; off >>= 1) a += __shfl_xor(a, off, 64);
            bool better = (a > best) || (a == best && ci[t] < bi);
            best = better ? a : best;
            bi = better ? ci[t] : bi;
        }
    }
    if (l == 0) {
        out[OUT_IDX + row] = (float)bi;
        maxsim[row] = (float)best;
        atomicAdd(counts + bi, 1);
    }
}

// ---------------- z_q gather (after rescore; overwrites scratch regions) ----------------
__global__ void eq_gather(const float* __restrict__ cb, float* __restrict__ out) {
    int w = threadIdx.x >> 6, l = threadIdx.x & 63;
    int row = blockIdx.x * 4 + w;
    int bi = (int)out[OUT_IDX + row];
    const float4* src = (const float4*)(cb + (size_t)bi * DD);
    float4* dst = (float4*)(out + (size_t)row * DD);
    dst[l] = src[l];
    dst[l + 64] = src[l + 64];
}

// ---------------- entropy + mean ----------------
__global__ void eq_entropy_mean(const int* __restrict__ counts,
                                const float* __restrict__ maxsim,
                                float* __restrict__ out) {
    __shared__ float red[16];
    int tid = threadIdx.x;   // 1024
    float s = 0.f;
    for (int b = tid; b < VOCAB; b += 1024) {
        int c = counts[b];
        if (c > 0) {
            float p = (float)c * (1.0f / 16384.0f);
            s += p * logf(p);
        }
    }
#pragma unroll
    for (int off = 32; off > 0; off >>= 1) s += __shfl_down(s, off, 64);
    if ((tid & 63) == 0) red[tid >> 6] = s;
    __syncthreads();
    if (tid == 0) {
        float t = 0.f;
#pragma unroll
        for (int i = 0; i < 16; ++i) t += red[i];
        out[OUT_ENT] = -t;
    }
    __syncthreads();
    float m = 0.f;
    for (int i = tid; i < NROW; i += 1024) m += maxsim[i];
#pragma unroll
    for (int off = 32; off > 0; off >>= 1) m += __shfl_down(m, off, 64);
    if ((tid & 63) == 0) red[tid >> 6] = m;
    __syncthreads();
    if (tid == 0) {
        float t = 0.f;
#pragma unroll
        for (int i = 0; i < 16; ++i) t += red[i];
        out[OUT_MEAN] = t * (1.0f / 16384.0f);
    }
}

extern "C" void kernel_launch(void* const* d_in, const int* in_sizes, int n_in,
                              void* d_out, int out_size, void* d_ws, size_t ws_size,
                              hipStream_t stream) {
    const float* x  = (const float*)d_in[0];
    const float* cb = (const float*)d_in[1];
    float* out = (float*)d_out;
    float* wsf = (float*)d_ws;
    int*   wsi = (int*)d_ws;

    float* cbnorm = wsf + WS_CBNORM;
    float* maxsim = wsf + WS_MAXSIM;
    int*   counts = wsi + WS_COUNTS;

    ushort* xbf   = (ushort*)out;                 // scratch in out
    ushort* cbbf  = (ushort*)(out + CBBF_W);
    float*  candv = out + CANDV_W;
    int*    candi = (int*)(out + CANDI_W);

    hipMemsetAsync(counts, 0, VOCAB * sizeof(int), stream);

    eq_prep_cb<<<VOCAB, 64, 0, stream>>>(cb, cbbf, cbnorm);
    eq_convx<<<4096, 256, 0, stream>>>(x, xbf);

    eq_gemm_topk<<<256, 512, 0, stream>>>(xbf, cbbf, candv, candi);

    eq_rescore<<<NROW / 4, 256, 0, stream>>>(x, cb, cbnorm, candv, candi, out, maxsim, counts);
    eq_gather<<<NROW / 4, 256, 0, stream>>>(cb, out);
    eq_entropy_mean<<<1, 1024, 0, stream>>>(counts, maxsim, out);
}

// Round 5
// 281.435 us; speedup vs baseline: 6.6213x; 1.1725x over previous
//
#include <hip/hip_runtime.h>

typedef short bf16x8 __attribute__((ext_vector_type(8)));
typedef float f32x4  __attribute__((ext_vector_type(4)));

#define NROW  16384
#define DD    512
#define VOCAB 8192
#define VS    4
#define VCH   2048           // vocab rows per split
#define BM    256            // vocab tile
#define BN    256            // x-row tile
#define BK    64
#define NCHUNK 8             // VCH/BM
#define NKT    8             // DD/BK
#define NTILE  64            // NCHUNK*NKT

// ---- out-buffer scratch layout (float words); all overwritten by final z_q ----
#define CBBF_W   4194304                 // cb normalized bf16 after x bf16
#define CANDV_W  6291456                 // [8][16384][2] float
#define CANDI_W  6815744                 // [8][16384][2] int
#define OUT_IDX  ((size_t)NROW * DD)
#define OUT_ENT  (OUT_IDX + NROW)
#define OUT_MEAN (OUT_ENT + 1)

// ---- ws layout (words) ----
#define WS_CBNORM 0
#define WS_MAXSIM 16384
#define WS_COUNTS 32768

#define GLD_LDS(g, l) \
    __builtin_amdgcn_global_load_lds((const __attribute__((address_space(1))) void*)(g), \
                                     (__attribute__((address_space(3))) void*)(l), 16, 0, 0)

#define BAR()   __builtin_amdgcn_s_barrier()
#define LGKM0() asm volatile("s_waitcnt lgkmcnt(0)" ::: "memory")
#define VM10()  asm volatile("s_waitcnt vmcnt(10)" ::: "memory")
#define VM6()   asm volatile("s_waitcnt vmcnt(6)" ::: "memory")
#define VM0()   asm volatile("s_waitcnt vmcnt(0)" ::: "memory")

__device__ __forceinline__ ushort f2bf(float f) {
    unsigned u = __float_as_uint(f);
    return (ushort)((u + 0x7fffu + ((u >> 16) & 1u)) >> 16);   // RNE
}

// ---------------- fused prep: x->bf16, cb->normalized bf16 + norms, zero counts ----------------
__global__ void eq_prep(const float* __restrict__ x, const float* __restrict__ cb,
                        ushort* __restrict__ xbf, ushort* __restrict__ cbbf,
                        float* __restrict__ nrm, int* __restrict__ counts) {
    const int b = blockIdx.x;
    const int tid = threadIdx.x;
    if (b < 4096) {
        // x conversion: 256 thr x 8 elems
        size_t i = ((size_t)b * 256 + tid) * 8;
        float4 v0 = *(const float4*)(x + i);
        float4 v1 = *(const float4*)(x + i + 4);
        ushort r[8] = {f2bf(v0.x), f2bf(v0.y), f2bf(v0.z), f2bf(v0.w),
                       f2bf(v1.x), f2bf(v1.y), f2bf(v1.z), f2bf(v1.w)};
        *(uint4*)(xbf + i) = *(const uint4*)r;
        return;
    }
    const int bb = b - 4096;                    // 0..2047
    if (bb < 32) counts[bb * 256 + tid] = 0;    // zero histogram (8192 ints)
    const int row = bb * 4 + (tid >> 6);        // 4 waves, 1 cb row each
    const int l = tid & 63;
    const float* p = cb + (size_t)row * DD;
    float4 a = *(const float4*)(p + l * 4);
    float4 bq = *(const float4*)(p + 256 + l * 4);
    float s = a.x * a.x + a.y * a.y + a.z * a.z + a.w * a.w
            + bq.x * bq.x + bq.y * bq.y + bq.z * bq.z + bq.w * bq.w;
#pragma unroll
    for (int off = 32; off > 0; off >>= 1) s += __shfl_xor(s, off, 64);
    float n = fmaxf(sqrtf(s), 1e-12f);
    float rn = 1.0f / n;
    ushort r0[4] = {f2bf(a.x * rn), f2bf(a.y * rn), f2bf(a.z * rn), f2bf(a.w * rn)};
    ushort r1[4] = {f2bf(bq.x * rn), f2bf(bq.y * rn), f2bf(bq.z * rn), f2bf(bq.w * rn)};
    *(uint2*)(cbbf + (size_t)row * DD + l * 4)       = *(const uint2*)r0;
    *(uint2*)(cbbf + (size_t)row * DD + 256 + l * 4) = *(const uint2*)r1;
    if (l == 0) nrm[row] = n;
}

// ---------------- MFMA candidate pass: 8-phase counted-vmcnt schedule ----------------
// Half-tiles split by K (256 rows x 32 K = 16 KB). 4 phases per K-tile:
//   p1(s0,nj01)+stage BKhi(t+1); p2(s0,nj23)+stage AKlo(t+2)+vmcnt(10);
//   p3(s1,nj01)+stage BKlo(t+2); p4(s1,nj23)+stage AKhi(t+2)+vmcnt(10).
// Raw s_barrier pairs per phase; never vmcnt(0) except the 2-tile tail.
__global__ __launch_bounds__(512, 2) void eq_gemm_topk(
    const ushort* __restrict__ xbf, const ushort* __restrict__ cbbf,
    float* __restrict__ candval, int* __restrict__ candidx) {
    __shared__ __align__(16) char LDS[131072];   // A: 2set x 2half x 16KB; B same @65536
    const int tid = threadIdx.x;
    const int lane = tid & 63;
    const int w = tid >> 6;          // 0..7
    const int wm = w >> 2;           // 0..1  -> 128 vocab rows
    const int wn = w & 3;            // 0..3  -> 64 x rows
    const int c = lane & 15, q = lane >> 4;

    // block mapping: XCD (bid&7) shares one vsplit's 2MB cb panel in L2
    const int bid = blockIdx.x;                  // 0..255
    const int vsplit = (bid & 7) >> 1;
    const int xtile  = ((bid >> 3) << 1) | (bid & 1);
    const int xbase  = xtile * BN;
    const int vsbase = vsplit * VCH;

    const char* gA = (const char*)cbbf + (size_t)vsbase * 1024;   // 1024 B per row
    const char* gB = (const char*)xbf  + (size_t)xbase  * 1024;
    // staging: lds unit u = (w*2+p)*64+lane -> row u>>2, slot (u&3)^(row&3)
    const int thrOff = (w * 32 + (lane >> 2)) * 1024
                     + (((lane & 3) ^ ((lane >> 2) & 3)) << 4);
    const int wp0 = w * 2048;
    // read-side: row r, k-slot q lives at unit 4r + (q ^ (r&3)); r&3 == c&3
    const int rdsw = (q ^ (c & 3)) << 4;
    const int aoff = (wm * 128 + c) * 64 + rdsw;
    const int boff = 65536 + (wn * 64 + c) * 64 + rdsw;

#define STAGE_A(lin2, h) do { int _l = (lin2); if (_l < NTILE) { \
        const char* _s = gA + ((_l >> 3) * 262144 + (_l & 7) * 128 + (h) * 64) + thrOff; \
        char* _d = (char*)LDS + ((_l & 1) * 32768 + (h) * 16384 + wp0); \
        GLD_LDS(_s, _d); GLD_LDS(_s + 16384, _d + 1024); } } while (0)
#define STAGE_B(lin2, h) do { int _l = (lin2); if (_l < NTILE) { \
        const char* _s = gB + ((_l & 7) * 128 + (h) * 64) + thrOff; \
        char* _d = (char*)LDS + (65536 + (_l & 1) * 32768 + (h) * 16384 + wp0); \
        GLD_LDS(_s, _d); GLD_LDS(_s + 16384, _d + 1024); } } while (0)

    int t1k[4], t2k[4];
#pragma unroll
    for (int nj = 0; nj < 4; ++nj) { t1k[nj] = 0x80000000; t2k[nj] = 0x80000000; }

    f32x4 acc[8][4];

    // prologue: 7 half-tiles in steady order; drain tile0's 4
    STAGE_A(0, 0); STAGE_B(0, 0); STAGE_A(0, 1); STAGE_B(0, 1);
    STAGE_A(1, 0); STAGE_B(1, 0); STAGE_A(1, 1);
    VM6(); BAR();

    for (int lin = 0; lin < NTILE; ++lin) {
        const int set = (lin & 1) * 32768;
        if ((lin & 7) == 0) {
#pragma unroll
            for (int mi = 0; mi < 8; ++mi)
#pragma unroll
                for (int nj = 0; nj < 4; ++nj) acc[mi][nj] = (f32x4){0.f, 0.f, 0.f, 0.f};
        }
        bf16x8 af[8], bf0, bf1;
        // ---- phase 1: s=0, nj 0/1 ----
#pragma unroll
        for (int mi = 0; mi < 8; ++mi)
            af[mi] = *(const bf16x8*)(LDS + set + aoff + mi * 1024);
        bf0 = *(const bf16x8*)(LDS + set + boff);
        bf1 = *(const bf16x8*)(LDS + set + boff + 1024);
        STAGE_B(lin + 1, 1);
        BAR(); LGKM0();
        __builtin_amdgcn_s_setprio(1);
#pragma unroll
        for (int mi = 0; mi < 8; ++mi) {
            acc[mi][0] = __builtin_amdgcn_mfma_f32_16x16x32_bf16(af[mi], bf0, acc[mi][0], 0, 0, 0);
            acc[mi][1] = __builtin_amdgcn_mfma_f32_16x16x32_bf16(af[mi], bf1, acc[mi][1], 0, 0, 0);
        }
        __builtin_amdgcn_s_setprio(0);
        BAR();
        // ---- phase 2: s=0, nj 2/3 ----
        bf0 = *(const bf16x8*)(LDS + set + boff + 2048);
        bf1 = *(const bf16x8*)(LDS + set + boff + 3072);
        STAGE_A(lin + 2, 0);
        if (lin < 62) { VM10(); } else { VM0(); }
        BAR(); LGKM0();
        __builtin_amdgcn_s_setprio(1);
#pragma unroll
        for (int mi = 0; mi < 8; ++mi) {
            acc[mi][2] = __builtin_amdgcn_mfma_f32_16x16x32_bf16(af[mi], bf0, acc[mi][2], 0, 0, 0);
            acc[mi][3] = __builtin_amdgcn_mfma_f32_16x16x32_bf16(af[mi], bf1, acc[mi][3], 0, 0, 0);
        }
        __builtin_amdgcn_s_setprio(0);
        BAR();
        // ---- phase 3: s=1, nj 0/1 ----
#pragma unroll
        for (int mi = 0; mi < 8; ++mi)
            af[mi] = *(const bf16x8*)(LDS + set + 16384 + aoff + mi * 1024);
        bf0 = *(const bf16x8*)(LDS + set + 16384 + boff);
        bf1 = *(const bf16x8*)(LDS + set + 16384 + boff + 1024);
        STAGE_B(lin + 2, 0);
        BAR(); LGKM0();
        __builtin_amdgcn_s_setprio(1);
#pragma unroll
        for (int mi = 0; mi < 8; ++mi) {
            acc[mi][0] = __builtin_amdgcn_mfma_f32_16x16x32_bf16(af[mi], bf0, acc[mi][0], 0, 0, 0);
            acc[mi][1] = __builtin_amdgcn_mfma_f32_16x16x32_bf16(af[mi], bf1, acc[mi][1], 0, 0, 0);
        }
        __builtin_amdgcn_s_setprio(0);
        BAR();
        // ---- phase 4: s=1, nj 2/3 ----
        bf0 = *(const bf16x8*)(LDS + set + 16384 + boff + 2048);
        bf1 = *(const bf16x8*)(LDS + set + 16384 + boff + 3072);
        STAGE_A(lin + 2, 1);
        if (lin < 62) { VM10(); } else { VM0(); }
        BAR(); LGKM0();
        __builtin_amdgcn_s_setprio(1);
#pragma unroll
        for (int mi = 0; mi < 8; ++mi) {
            acc[mi][2] = __builtin_amdgcn_mfma_f32_16x16x32_bf16(af[mi], bf0, acc[mi][2], 0, 0, 0);
            acc[mi][3] = __builtin_amdgcn_mfma_f32_16x16x32_bf16(af[mi], bf1, acc[mi][3], 0, 0, 0);
        }
        __builtin_amdgcn_s_setprio(0);
        BAR();
        // ---- chunk fold: packed-key top-2 (5 VALU/value) ----
        if ((lin & 7) == 7) {
            const int chb = (lin >> 3) << 5;
#pragma unroll
            for (int nj = 0; nj < 4; ++nj)
#pragma unroll
                for (int mi = 0; mi < 8; ++mi)
#pragma unroll
                    for (int r = 0; r < 4; ++r) {
                        int key = (__float_as_int(acc[mi][nj][r]) & (int)0xFFFFFF00)
                                | (chb + mi * 4 + r);
                        int mn = t1k[nj] < key ? t1k[nj] : key;
                        t1k[nj] = t1k[nj] < key ? key : t1k[nj];
                        t2k[nj] = t2k[nj] < mn ? mn : t2k[nj];
                    }
        }
    }
    // decode keys -> (value, vocab idx), exact merge across the 4 q-lanes
#pragma unroll
    for (int nj = 0; nj < 4; ++nj) {
        int k1 = t1k[nj], k2 = t2k[nj];
        float t1v = __int_as_float(k1 & (int)0xFFFFFF00);
        float t2v = __int_as_float(k2 & (int)0xFFFFFF00);
        int l1 = k1 & 255, l2 = k2 & 255;
        int t1i = vsbase + ((l1 >> 5) << 8) + (wm << 7) + (((l1 >> 2) & 7) << 4) + (q << 2) + (l1 & 3);
        int t2i = vsbase + ((l2 >> 5) << 8) + (wm << 7) + (((l2 >> 2) & 7) << 4) + (q << 2) + (l2 & 3);
#pragma unroll
        for (int off = 16; off <= 32; off <<= 1) {
            float o1v = __shfl_xor(t1v, off, 64); int o1i = __shfl_xor(t1i, off, 64);
            float o2v = __shfl_xor(t2v, off, 64); int o2i = __shfl_xor(t2i, off, 64);
            bool wbest = (t1v > o1v) || (t1v == o1v && t1i < o1i);
            float m1 = wbest ? t1v : o1v;  int m1i = wbest ? t1i : o1i;
            float ca = wbest ? o1v : t1v;  int cai = wbest ? o1i : t1i;
            float cw = wbest ? t2v : o2v;  int cwi = wbest ? t2i : o2i;
            bool s2 = (ca > cw) || (ca == cw && cai < cwi);
            t1v = m1;           t1i = m1i;
            t2v = s2 ? ca : cw; t2i = s2 ? cai : cwi;
        }
        if (q == 0) {
            int list = vsplit * 2 + wm;
            int row = xbase + wn * 64 + nj * 16 + c;
            size_t base = ((size_t)list * NROW + row) * 2;
            candval[base] = t1v; candval[base + 1] = t2v;
            candidx[base] = t1i; candidx[base + 1] = t2i;
        }
    }
#undef STAGE_A
#undef STAGE_B
}

// ---------------- fp64 rescore with margin prefilter ----------------
__global__ void eq_rescore(const float* __restrict__ x, const float* __restrict__ cb,
                           const float* __restrict__ cbnorm,
                           const float* __restrict__ candval, const int* __restrict__ candidx,
                           float* __restrict__ out, float* __restrict__ maxsim,
                           int* __restrict__ counts) {
    int w = threadIdx.x >> 6, l = threadIdx.x & 63;
    int row = blockIdx.x * 4 + w;

    const float4* X4 = (const float4*)(x + (size_t)row * DD);
    float4 xa = X4[l], xb = X4[l + 64];
    float s2 = xa.x * xa.x + xa.y * xa.y + xa.z * xa.z + xa.w * xa.w
             + xb.x * xb.x + xb.y * xb.y + xb.z * xb.z + xb.w * xb.w;
#pragma unroll
    for (int off = 32; off > 0; off >>= 1) s2 += __shfl_xor(s2, off, 64);
    float xn = fmaxf(sqrtf(s2), 1e-12f);
    double xd[8] = {(double)(xa.x / xn), (double)(xa.y / xn), (double)(xa.z / xn),
                    (double)(xa.w / xn), (double)(xb.x / xn), (double)(xb.y / xn),
                    (double)(xb.z / xn), (double)(xb.w / xn)};

    float cv[16]; int ci[16];
#pragma unroll
    for (int t = 0; t < 16; ++t) {
        size_t b = ((size_t)(t >> 1) * NROW + row) * 2 + (t & 1);
        cv[t] = candval[b]; ci[t] = candidx[b];
    }
    float bv1 = cv[0];
#pragma unroll
    for (int t = 1; t < 16; ++t) bv1 = fmaxf(bv1, cv[t]);
    // candval scale is ||x||*sim; bf16 noise ~1e-4*||x|| + 3e-5 key trunc -> 2e-3 covers
    float margin = 2e-3f * xn;

    double best = -1e300; int bi = 1 << 30;
    for (int t = 0; t < 16; ++t) {
        if (cv[t] >= bv1 - margin) {                 // wave-uniform branch
            float n = cbnorm[ci[t]];
            const float4* C4 = (const float4*)(cb + (size_t)ci[t] * DD);
            float4 ca = C4[l], cb4 = C4[l + 64];
            double a = xd[0] * (double)(ca.x / n) + xd[1] * (double)(ca.y / n)
                     + xd[2] * (double)(ca.z / n) + xd[3] * (double)(ca.w / n)
                     + xd[4] * (double)(cb4.x / n) + xd[5] * (double)(cb4.y / n)
                     + xd[6] * (double)(cb4.z / n) + xd[7] * (double)(cb4.w / n);
#pragma unroll
            for (int off = 32; off > 0; off >>= 1) a += __shfl_xor(a, off, 64);
            bool better = (a > best) || (a == best && ci[t] < bi);
            best = better ? a : best;
            bi = better ? ci[t] : bi;
        }
    }
    if (l == 0) {
        out[OUT_IDX + row] = (float)bi;
        maxsim[row] = (float)best;
        atomicAdd(counts + bi, 1);
    }
}

// ---------------- z_q gather (after rescore; overwrites scratch regions) ----------------
__global__ void eq_gather(const float* __restrict__ cb, float* __restrict__ out) {
    int w = threadIdx.x >> 6, l = threadIdx.x & 63;
    int row = blockIdx.x * 4 + w;
    int bi = (int)out[OUT_IDX + row];
    const float4* src = (const float4*)(cb + (size_t)bi * DD);
    float4* dst = (float4*)(out + (size_t)row * DD);
    dst[l] = src[l];
    dst[l + 64] = src[l + 64];
}

// ---------------- entropy + mean ----------------
__global__ void eq_entropy_mean(const int* __restrict__ counts,
                                const float* __restrict__ maxsim,
                                float* __restrict__ out) {
    __shared__ float red[16];
    int tid = threadIdx.x;   // 1024
    float s = 0.f;
    for (int b = tid; b < VOCAB; b += 1024) {
        int c = counts[b];
        if (c > 0) {
            float p = (float)c * (1.0f / 16384.0f);
            s += p * logf(p);
        }
    }
#pragma unroll
    for (int off = 32; off > 0; off >>= 1) s += __shfl_down(s, off, 64);
    if ((tid & 63) == 0) red[tid >> 6] = s;
    __syncthreads();
    if (tid == 0) {
        float t = 0.f;
#pragma unroll
        for (int i = 0; i < 16; ++i) t += red[i];
        out[OUT_ENT] = -t;
    }
    __syncthreads();
    float m = 0.f;
    for (int i = tid; i < NROW; i += 1024) m += maxsim[i];
#pragma unroll
    for (int off = 32; off > 0; off >>= 1) m += __shfl_down(m, off, 64);
    if ((tid & 63) == 0) red[tid >> 6] = m;
    __syncthreads();
    if (tid == 0) {
        float t = 0.f;
#pragma unroll
        for (int i = 0; i < 16; ++i) t += red[i];
        out[OUT_MEAN] = t * (1.0f / 16384.0f);
    }
}

extern "C" void kernel_launch(void* const* d_in, const int* in_sizes, int n_in,
                              void* d_out, int out_size, void* d_ws, size_t ws_size,
                              hipStream_t stream) {
    const float* x  = (const float*)d_in[0];
    const float* cb = (const float*)d_in[1];
    float* out = (float*)d_out;
    float* wsf = (float*)d_ws;
    int*   wsi = (int*)d_ws;

    float* cbnorm = wsf + WS_CBNORM;
    float* maxsim = wsf + WS_MAXSIM;
    int*   counts = wsi + WS_COUNTS;

    ushort* xbf   = (ushort*)out;                 // scratch in out
    ushort* cbbf  = (ushort*)(out + CBBF_W);
    float*  candv = out + CANDV_W;
    int*    candi = (int*)(out + CANDI_W);

    eq_prep<<<6144, 256, 0, stream>>>(x, cb, xbf, cbbf, cbnorm, counts);

    eq_gemm_topk<<<256, 512, 0, stream>>>(xbf, cbbf, candv, candi);

    eq_rescore<<<NROW / 4, 256, 0, stream>>>(x, cb, cbnorm, candv, candi, out, maxsim, counts);
    eq_gather<<<NROW / 4, 256, 0, stream>>>(cb, out);
    eq_entropy_mean<<<1, 1024, 0, stream>>>(counts, maxsim, out);
}

// Round 6
// 261.984 us; speedup vs baseline: 7.1129x; 1.0742x over previous
//
#include <hip/hip_runtime.h>

typedef short bf16x8 __attribute__((ext_vector_type(8)));
typedef float f32x4  __attribute__((ext_vector_type(4)));

#define NROW  16384
#define DD    512
#define VOCAB 8192
#define VS    4
#define VCH   2048           // vocab rows per split
#define BM    256            // vocab tile
#define BN    256            // x-row tile
#define BK    64
#define NCHUNK 8             // VCH/BM
#define NKT    8             // DD/BK
#define NTILE  64            // NCHUNK*NKT

// ---- out-buffer scratch layout (float words); all overwritten by final z_q ----
#define CBBF_W   4194304                 // cb normalized bf16 after x bf16
#define CANDV_W  6291456                 // fallback: [8][16384][2] float
#define CANDI_W  6815744                 // fallback: [8][16384][2] int
#define OUT_IDX  ((size_t)NROW * DD)
#define OUT_ENT  (OUT_IDX + NROW)
#define OUT_MEAN (OUT_ENT + 1)

// ---- ws layout (words) ----
#define WS_CBNORM 0
#define WS_MAXSIM 16384
#define WS_COUNTS 32768
#define WS_CANDV  49152
#define WS_CANDI  311296
#define WS_NEED_BYTES ((size_t)(311296 + 262144) * 4)   // 2,293,760 B

#define GLD_LDS(g, l) \
    __builtin_amdgcn_global_load_lds((const __attribute__((address_space(1))) void*)(g), \
                                     (__attribute__((address_space(3))) void*)(l), 16, 0, 0)

#define BAR()   __builtin_amdgcn_s_barrier()
#define LGKM0() asm volatile("s_waitcnt lgkmcnt(0)" ::: "memory")
#define VM10()  asm volatile("s_waitcnt vmcnt(10)" ::: "memory")
#define VM6()   asm volatile("s_waitcnt vmcnt(6)" ::: "memory")
#define VM0()   asm volatile("s_waitcnt vmcnt(0)" ::: "memory")

__device__ __forceinline__ ushort f2bf(float f) {
    unsigned u = __float_as_uint(f);
    return (ushort)((u + 0x7fffu + ((u >> 16) & 1u)) >> 16);   // RNE
}

// ---------------- fused prep: x->bf16, cb->normalized bf16 + norms, zero counts ----------------
__global__ void eq_prep(const float* __restrict__ x, const float* __restrict__ cb,
                        ushort* __restrict__ xbf, ushort* __restrict__ cbbf,
                        float* __restrict__ nrm, int* __restrict__ counts) {
    const int b = blockIdx.x;
    const int tid = threadIdx.x;
    if (b < 4096) {
        size_t i = ((size_t)b * 256 + tid) * 8;
        float4 v0 = *(const float4*)(x + i);
        float4 v1 = *(const float4*)(x + i + 4);
        ushort r[8] = {f2bf(v0.x), f2bf(v0.y), f2bf(v0.z), f2bf(v0.w),
                       f2bf(v1.x), f2bf(v1.y), f2bf(v1.z), f2bf(v1.w)};
        *(uint4*)(xbf + i) = *(const uint4*)r;
        return;
    }
    const int bb = b - 4096;                    // 0..2047
    if (bb < 32) counts[bb * 256 + tid] = 0;    // zero histogram (8192 ints)
    const int row = bb * 4 + (tid >> 6);        // 4 waves, 1 cb row each
    const int l = tid & 63;
    const float* p = cb + (size_t)row * DD;
    float4 a = *(const float4*)(p + l * 4);
    float4 bq = *(const float4*)(p + 256 + l * 4);
    float s = a.x * a.x + a.y * a.y + a.z * a.z + a.w * a.w
            + bq.x * bq.x + bq.y * bq.y + bq.z * bq.z + bq.w * bq.w;
#pragma unroll
    for (int off = 32; off > 0; off >>= 1) s += __shfl_xor(s, off, 64);
    float n = fmaxf(sqrtf(s), 1e-12f);
    float rn = 1.0f / n;
    ushort r0[4] = {f2bf(a.x * rn), f2bf(a.y * rn), f2bf(a.z * rn), f2bf(a.w * rn)};
    ushort r1[4] = {f2bf(bq.x * rn), f2bf(bq.y * rn), f2bf(bq.z * rn), f2bf(bq.w * rn)};
    *(uint2*)(cbbf + (size_t)row * DD + l * 4)       = *(const uint2*)r0;
    *(uint2*)(cbbf + (size_t)row * DD + 256 + l * 4) = *(const uint2*)r1;
    if (l == 0) nrm[row] = n;
}

// ---------------- MFMA candidate pass: 8-phase counted-vmcnt schedule ----------------
// Half-tiles split by K (256 rows x 32 K = 16 KB). Slot permutation within each
// half: physical slot s = k ^ ((r>>1)&3)  [conflict-free: 8-lane bank-groups
// (4c + q^((c>>1)&3)) mod 8 form a perfect permutation]. Linear gload_lds dest,
// inverse permutation folded into the global source offset (rule #21).
__global__ __launch_bounds__(512, 2) void eq_gemm_topk(
    const ushort* __restrict__ xbf, const ushort* __restrict__ cbbf,
    float* __restrict__ candval, int* __restrict__ candidx) {
    __shared__ __align__(16) char LDS[131072];   // A: 2set x 2half x 16KB; B same @65536
    const int tid = threadIdx.x;
    const int lane = tid & 63;
    const int w = tid >> 6;          // 0..7
    const int wm = w >> 2;           // 0..1  -> 128 vocab rows
    const int wn = w & 3;            // 0..3  -> 64 x rows
    const int c = lane & 15, q = lane >> 4;

    // block mapping: XCD (bid&7) shares one vsplit's 2MB cb panel in L2
    const int bid = blockIdx.x;                  // 0..255
    const int vsplit = (bid & 7) >> 1;
    const int xtile  = ((bid >> 3) << 1) | (bid & 1);
    const int xbase  = xtile * BN;
    const int vsbase = vsplit * VCH;

    const char* gA = (const char*)cbbf + (size_t)vsbase * 1024;   // 1024 B per row
    const char* gB = (const char*)xbf  + (size_t)xbase  * 1024;
    // staging: unit u = w*128 + lane (+64 for 2nd load) -> row u>>2, slot u&3,
    // logical k = (lane&3) ^ ((lane>>3)&3)  [invariant across both loads]
    const int thrOff = (w * 32 + (lane >> 2)) * 1024
                     + ((((lane & 3) ^ ((lane >> 3) & 3))) << 4);
    const int wp0 = w * 2048;
    // read-side: row r, logical kslot q at physical slot q ^ ((r>>1)&3); (r>>1)&3 == (c>>1)&3
    const int rdsw = (q ^ ((c >> 1) & 3)) << 4;
    const int aoff = (wm * 128 + c) * 64 + rdsw;
    const int boff = 65536 + (wn * 64 + c) * 64 + rdsw;

#define STAGE_A(lin2, h) do { int _l = (lin2); if (_l < NTILE) { \
        const char* _s = gA + ((_l >> 3) * 262144 + (_l & 7) * 128 + (h) * 64) + thrOff; \
        char* _d = (char*)LDS + ((_l & 1) * 32768 + (h) * 16384 + wp0); \
        GLD_LDS(_s, _d); GLD_LDS(_s + 16384, _d + 1024); } } while (0)
#define STAGE_B(lin2, h) do { int _l = (lin2); if (_l < NTILE) { \
        const char* _s = gB + ((_l & 7) * 128 + (h) * 64) + thrOff; \
        char* _d = (char*)LDS + (65536 + (_l & 1) * 32768 + (h) * 16384 + wp0); \
        GLD_LDS(_s, _d); GLD_LDS(_s + 16384, _d + 1024); } } while (0)

    int t1k[4], t2k[4];
#pragma unroll
    for (int nj = 0; nj < 4; ++nj) { t1k[nj] = 0x80000000; t2k[nj] = 0x80000000; }

    f32x4 acc[8][4];

    // prologue: 7 half-tiles in steady order; drain tile0's 4
    STAGE_A(0, 0); STAGE_B(0, 0); STAGE_A(0, 1); STAGE_B(0, 1);
    STAGE_A(1, 0); STAGE_B(1, 0); STAGE_A(1, 1);
    VM6(); BAR();

    for (int lin = 0; lin < NTILE; ++lin) {
        const int set = (lin & 1) * 32768;
        if ((lin & 7) == 0) {
#pragma unroll
            for (int mi = 0; mi < 8; ++mi)
#pragma unroll
                for (int nj = 0; nj < 4; ++nj) acc[mi][nj] = (f32x4){0.f, 0.f, 0.f, 0.f};
        }
        bf16x8 af[8], bf0, bf1;
        // ---- phase 1: s=0, nj 0/1 ----
#pragma unroll
        for (int mi = 0; mi < 8; ++mi)
            af[mi] = *(const bf16x8*)(LDS + set + aoff + mi * 1024);
        bf0 = *(const bf16x8*)(LDS + set + boff);
        bf1 = *(const bf16x8*)(LDS + set + boff + 1024);
        STAGE_B(lin + 1, 1);
        BAR(); LGKM0();
        __builtin_amdgcn_s_setprio(1);
#pragma unroll
        for (int mi = 0; mi < 8; ++mi) {
            acc[mi][0] = __builtin_amdgcn_mfma_f32_16x16x32_bf16(af[mi], bf0, acc[mi][0], 0, 0, 0);
            acc[mi][1] = __builtin_amdgcn_mfma_f32_16x16x32_bf16(af[mi], bf1, acc[mi][1], 0, 0, 0);
        }
        __builtin_amdgcn_s_setprio(0);
        BAR();
        // ---- phase 2: s=0, nj 2/3 ----
        bf0 = *(const bf16x8*)(LDS + set + boff + 2048);
        bf1 = *(const bf16x8*)(LDS + set + boff + 3072);
        STAGE_A(lin + 2, 0);
        if (lin < 62) { VM10(); } else { VM0(); }
        BAR(); LGKM0();
        __builtin_amdgcn_s_setprio(1);
#pragma unroll
        for (int mi = 0; mi < 8; ++mi) {
            acc[mi][2] = __builtin_amdgcn_mfma_f32_16x16x32_bf16(af[mi], bf0, acc[mi][2], 0, 0, 0);
            acc[mi][3] = __builtin_amdgcn_mfma_f32_16x16x32_bf16(af[mi], bf1, acc[mi][3], 0, 0, 0);
        }
        __builtin_amdgcn_s_setprio(0);
        BAR();
        // ---- phase 3: s=1, nj 0/1 ----
#pragma unroll
        for (int mi = 0; mi < 8; ++mi)
            af[mi] = *(const bf16x8*)(LDS + set + 16384 + aoff + mi * 1024);
        bf0 = *(const bf16x8*)(LDS + set + 16384 + boff);
        bf1 = *(const bf16x8*)(LDS + set + 16384 + boff + 1024);
        STAGE_B(lin + 2, 0);
        BAR(); LGKM0();
        __builtin_amdgcn_s_setprio(1);
#pragma unroll
        for (int mi = 0; mi < 8; ++mi) {
            acc[mi][0] = __builtin_amdgcn_mfma_f32_16x16x32_bf16(af[mi], bf0, acc[mi][0], 0, 0, 0);
            acc[mi][1] = __builtin_amdgcn_mfma_f32_16x16x32_bf16(af[mi], bf1, acc[mi][1], 0, 0, 0);
        }
        __builtin_amdgcn_s_setprio(0);
        BAR();
        // ---- phase 4: s=1, nj 2/3 ----
        bf0 = *(const bf16x8*)(LDS + set + 16384 + boff + 2048);
        bf1 = *(const bf16x8*)(LDS + set + 16384 + boff + 3072);
        STAGE_A(lin + 2, 1);
        if (lin < 62) { VM10(); } else { VM0(); }
        BAR(); LGKM0();
        __builtin_amdgcn_s_setprio(1);
#pragma unroll
        for (int mi = 0; mi < 8; ++mi) {
            acc[mi][2] = __builtin_amdgcn_mfma_f32_16x16x32_bf16(af[mi], bf0, acc[mi][2], 0, 0, 0);
            acc[mi][3] = __builtin_amdgcn_mfma_f32_16x16x32_bf16(af[mi], bf1, acc[mi][3], 0, 0, 0);
        }
        __builtin_amdgcn_s_setprio(0);
        BAR();
        // ---- chunk fold: packed-key top-2 (5 VALU/value) ----
        if ((lin & 7) == 7) {
            const int chb = (lin >> 3) << 5;
#pragma unroll
            for (int nj = 0; nj < 4; ++nj)
#pragma unroll
                for (int mi = 0; mi < 8; ++mi)
#pragma unroll
                    for (int r = 0; r < 4; ++r) {
                        int key = (__float_as_int(acc[mi][nj][r]) & (int)0xFFFFFF00)
                                | (chb + mi * 4 + r);
                        int mn = t1k[nj] < key ? t1k[nj] : key;
                        t1k[nj] = t1k[nj] < key ? key : t1k[nj];
                        t2k[nj] = t2k[nj] < mn ? mn : t2k[nj];
                    }
        }
    }
    // decode keys -> (value, vocab idx), exact merge across the 4 q-lanes
#pragma unroll
    for (int nj = 0; nj < 4; ++nj) {
        int k1 = t1k[nj], k2 = t2k[nj];
        float t1v = __int_as_float(k1 & (int)0xFFFFFF00);
        float t2v = __int_as_float(k2 & (int)0xFFFFFF00);
        int l1 = k1 & 255, l2 = k2 & 255;
        int t1i = vsbase + ((l1 >> 5) << 8) + (wm << 7) + (((l1 >> 2) & 7) << 4) + (q << 2) + (l1 & 3);
        int t2i = vsbase + ((l2 >> 5) << 8) + (wm << 7) + (((l2 >> 2) & 7) << 4) + (q << 2) + (l2 & 3);
#pragma unroll
        for (int off = 16; off <= 32; off <<= 1) {
            float o1v = __shfl_xor(t1v, off, 64); int o1i = __shfl_xor(t1i, off, 64);
            float o2v = __shfl_xor(t2v, off, 64); int o2i = __shfl_xor(t2i, off, 64);
            bool wbest = (t1v > o1v) || (t1v == o1v && t1i < o1i);
            float m1 = wbest ? t1v : o1v;  int m1i = wbest ? t1i : o1i;
            float ca = wbest ? o1v : t1v;  int cai = wbest ? o1i : t1i;
            float cw = wbest ? t2v : o2v;  int cwi = wbest ? t2i : o2i;
            bool s2 = (ca > cw) || (ca == cw && cai < cwi);
            t1v = m1;           t1i = m1i;
            t2v = s2 ? ca : cw; t2i = s2 ? cai : cwi;
        }
        if (q == 0) {
            int list = vsplit * 2 + wm;
            int row = xbase + wn * 64 + nj * 16 + c;
            size_t base = ((size_t)list * NROW + row) * 2;
            candval[base] = t1v; candval[base + 1] = t2v;
            candidx[base] = t1i; candidx[base + 1] = t2i;
        }
    }
#undef STAGE_A
#undef STAGE_B
}

// ---------------- fp64 rescore with margin prefilter (+ optional fused z_q gather) ----------------
template <bool FUSE_ZQ>
__device__ __forceinline__ void rescore_body(
    const float* __restrict__ x, const float* __restrict__ cb,
    const float* __restrict__ cbnorm,
    const float* __restrict__ candval, const int* __restrict__ candidx,
    float* __restrict__ out, float* __restrict__ maxsim, int* __restrict__ counts) {
    int w = threadIdx.x >> 6, l = threadIdx.x & 63;
    int row = blockIdx.x * 4 + w;

    const float4* X4 = (const float4*)(x + (size_t)row * DD);
    float4 xa = X4[l], xb = X4[l + 64];
    float s2 = xa.x * xa.x + xa.y * xa.y + xa.z * xa.z + xa.w * xa.w
             + xb.x * xb.x + xb.y * xb.y + xb.z * xb.z + xb.w * xb.w;
#pragma unroll
    for (int off = 32; off > 0; off >>= 1) s2 += __shfl_xor(s2, off, 64);
    float xn = fmaxf(sqrtf(s2), 1e-12f);
    double xd[8] = {(double)(xa.x / xn), (double)(xa.y / xn), (double)(xa.z / xn),
                    (double)(xa.w / xn), (double)(xb.x / xn), (double)(xb.y / xn),
                    (double)(xb.z / xn), (double)(xb.w / xn)};

    float cv[16]; int ci[16];
#pragma unroll
    for (int t = 0; t < 16; ++t) {
        size_t b = ((size_t)(t >> 1) * NROW + row) * 2 + (t & 1);
        cv[t] = candval[b]; ci[t] = candidx[b];
    }
    float bv1 = cv[0];
#pragma unroll
    for (int t = 1; t < 16; ++t) bv1 = fmaxf(bv1, cv[t]);
    // candval scale is ||x||*sim; bf16 noise ~1e-4*||x|| + 3e-5 key trunc -> 2e-3 covers
    float margin = 2e-3f * xn;

    double best = -1e300; int bi = 1 << 30;
    for (int t = 0; t < 16; ++t) {
        if (cv[t] >= bv1 - margin) {                 // wave-uniform branch
            float n = cbnorm[ci[t]];
            const float4* C4 = (const float4*)(cb + (size_t)ci[t] * DD);
            float4 ca = C4[l], cb4 = C4[l + 64];
            double a = xd[0] * (double)(ca.x / n) + xd[1] * (double)(ca.y / n)
                     + xd[2] * (double)(ca.z / n) + xd[3] * (double)(ca.w / n)
                     + xd[4] * (double)(cb4.x / n) + xd[5] * (double)(cb4.y / n)
                     + xd[6] * (double)(cb4.z / n) + xd[7] * (double)(cb4.w / n);
#pragma unroll
            for (int off = 32; off > 0; off >>= 1) a += __shfl_xor(a, off, 64);
            bool better = (a > best) || (a == best && ci[t] < bi);
            best = better ? a : best;     // wave-uniform after reduction
            bi = better ? ci[t] : bi;
        }
    }
    if (l == 0) {
        out[OUT_IDX + row] = (float)bi;
        maxsim[row] = (float)best;
        atomicAdd(counts + bi, 1);
    }
    if (FUSE_ZQ) {
        const float4* src = (const float4*)(cb + (size_t)bi * DD);
        float4* dst = (float4*)(out + (size_t)row * DD);
        dst[l] = src[l];
        dst[l + 64] = src[l + 64];
    }
}

__global__ void eq_rescore(const float* __restrict__ x, const float* __restrict__ cb,
                           const float* __restrict__ cbnorm,
                           const float* __restrict__ candval, const int* __restrict__ candidx,
                           float* __restrict__ out, float* __restrict__ maxsim,
                           int* __restrict__ counts) {
    rescore_body<false>(x, cb, cbnorm, candval, candidx, out, maxsim, counts);
}

__global__ void eq_rescore_fused(const float* __restrict__ x, const float* __restrict__ cb,
                                 const float* __restrict__ cbnorm,
                                 const float* __restrict__ candval, const int* __restrict__ candidx,
                                 float* __restrict__ out, float* __restrict__ maxsim,
                                 int* __restrict__ counts) {
    rescore_body<true>(x, cb, cbnorm, candval, candidx, out, maxsim, counts);
}

// ---------------- z_q gather (fallback path only) ----------------
__global__ void eq_gather(const float* __restrict__ cb, float* __restrict__ out) {
    int w = threadIdx.x >> 6, l = threadIdx.x & 63;
    int row = blockIdx.x * 4 + w;
    int bi = (int)out[OUT_IDX + row];
    const float4* src = (const float4*)(cb + (size_t)bi * DD);
    float4* dst = (float4*)(out + (size_t)row * DD);
    dst[l] = src[l];
    dst[l + 64] = src[l + 64];
}

// ---------------- entropy + mean ----------------
__global__ void eq_entropy_mean(const int* __restrict__ counts,
                                const float* __restrict__ maxsim,
                                float* __restrict__ out) {
    __shared__ float red[16];
    int tid = threadIdx.x;   // 1024
    float s = 0.f;
    for (int b = tid; b < VOCAB; b += 1024) {
        int c = counts[b];
        if (c > 0) {
            float p = (float)c * (1.0f / 16384.0f);
            s += p * logf(p);
        }
    }
#pragma unroll
    for (int off = 32; off > 0; off >>= 1) s += __shfl_down(s, off, 64);
    if ((tid & 63) == 0) red[tid >> 6] = s;
    __syncthreads();
    if (tid == 0) {
        float t = 0.f;
#pragma unroll
        for (int i = 0; i < 16; ++i) t += red[i];
        out[OUT_ENT] = -t;
    }
    __syncthreads();
    float m = 0.f;
    for (int i = tid; i < NROW; i += 1024) m += maxsim[i];
#pragma unroll
    for (int off = 32; off > 0; off >>= 1) m += __shfl_down(m, off, 64);
    if ((tid & 63) == 0) red[tid >> 6] = m;
    __syncthreads();
    if (tid == 0) {
        float t = 0.f;
#pragma unroll
        for (int i = 0; i < 16; ++i) t += red[i];
        out[OUT_MEAN] = t * (1.0f / 16384.0f);
    }
}

extern "C" void kernel_launch(void* const* d_in, const int* in_sizes, int n_in,
                              void* d_out, int out_size, void* d_ws, size_t ws_size,
                              hipStream_t stream) {
    const float* x  = (const float*)d_in[0];
    const float* cb = (const float*)d_in[1];
    float* out = (float*)d_out;
    float* wsf = (float*)d_ws;
    int*   wsi = (int*)d_ws;

    float* cbnorm = wsf + WS_CBNORM;
    float* maxsim = wsf + WS_MAXSIM;
    int*   counts = wsi + WS_COUNTS;

    ushort* xbf   = (ushort*)out;                 // scratch in out
    ushort* cbbf  = (ushort*)(out + CBBF_W);

    const bool fused = ws_size >= WS_NEED_BYTES;  // deterministic per deployment
    float* candv = fused ? (wsf + WS_CANDV) : (out + CANDV_W);
    int*   candi = fused ? (wsi + WS_CANDI) : (int*)(out + CANDI_W);

    eq_prep<<<6144, 256, 0, stream>>>(x, cb, xbf, cbbf, cbnorm, counts);

    eq_gemm_topk<<<256, 512, 0, stream>>>(xbf, cbbf, candv, candi);

    if (fused) {
        eq_rescore_fused<<<NROW / 4, 256, 0, stream>>>(x, cb, cbnorm, candv, candi,
                                                       out, maxsim, counts);
    } else {
        eq_rescore<<<NROW / 4, 256, 0, stream>>>(x, cb, cbnorm, candv, candi,
                                                 out, maxsim, counts);
        eq_gather<<<NROW / 4, 256, 0, stream>>>(cb, out);
    }
    eq_entropy_mean<<<1, 1024, 0, stream>>>(counts, maxsim, out);
}

// Round 7
// 255.250 us; speedup vs baseline: 7.3006x; 1.0264x over previous
//
#include <hip/hip_runtime.h>

typedef short bf16x8 __attribute__((ext_vector_type(8)));
typedef float f32x4  __attribute__((ext_vector_type(4)));

#define NROW  16384
#define DD    512
#define VOCAB 8192
#define VS    4
#define VCH   2048           // vocab rows per split
#define BM    256            // vocab tile
#define BN    256            // x-row tile
#define BK    64
#define NCHUNK 8             // VCH/BM
#define NKT    8             // DD/BK
#define NTILE  64            // NCHUNK*NKT

// ---- out-buffer scratch layout (float words); all overwritten by final z_q ----
#define CBBF_W   4194304                 // cb normalized bf16 after x bf16
#define CANDV_W  6291456                 // fallback: [8][16384][2] float
#define CANDI_W  6815744                 // fallback: [8][16384][2] int
#define OUT_IDX  ((size_t)NROW * DD)
#define OUT_ENT  (OUT_IDX + NROW)
#define OUT_MEAN (OUT_ENT + 1)

// ---- ws layout (words) ----
#define WS_CBNORM 0
#define WS_MAXSIM 16384
#define WS_COUNTS 32768
#define WS_CANDV  49152
#define WS_CANDI  311296
#define WS_NEED_BYTES ((size_t)(311296 + 262144) * 4)   // 2,293,760 B

#define GLD_LDS(g, l) \
    __builtin_amdgcn_global_load_lds((const __attribute__((address_space(1))) void*)(g), \
                                     (__attribute__((address_space(3))) void*)(l), 16, 0, 0)

#define BAR()   __builtin_amdgcn_s_barrier()
#define LGKM0() asm volatile("s_waitcnt lgkmcnt(0)" ::: "memory")
#define VM4()   asm volatile("s_waitcnt vmcnt(4)" ::: "memory")
#define VM0()   asm volatile("s_waitcnt vmcnt(0)" ::: "memory")

__device__ __forceinline__ ushort f2bf(float f) {
    unsigned u = __float_as_uint(f);
    return (ushort)((u + 0x7fffu + ((u >> 16) & 1u)) >> 16);   // RNE
}

// ---------------- fused prep: x->bf16, cb->normalized bf16 + norms, zero counts ----------------
__global__ void eq_prep(const float* __restrict__ x, const float* __restrict__ cb,
                        ushort* __restrict__ xbf, ushort* __restrict__ cbbf,
                        float* __restrict__ nrm, int* __restrict__ counts) {
    const int b = blockIdx.x;
    const int tid = threadIdx.x;
    if (b < 4096) {
        size_t i = ((size_t)b * 256 + tid) * 8;
        float4 v0 = *(const float4*)(x + i);
        float4 v1 = *(const float4*)(x + i + 4);
        ushort r[8] = {f2bf(v0.x), f2bf(v0.y), f2bf(v0.z), f2bf(v0.w),
                       f2bf(v1.x), f2bf(v1.y), f2bf(v1.z), f2bf(v1.w)};
        *(uint4*)(xbf + i) = *(const uint4*)r;
        return;
    }
    const int bb = b - 4096;                    // 0..2047
    if (bb < 32) counts[bb * 256 + tid] = 0;    // zero histogram (8192 ints)
    const int row = bb * 4 + (tid >> 6);        // 4 waves, 1 cb row each
    const int l = tid & 63;
    const float* p = cb + (size_t)row * DD;
    float4 a = *(const float4*)(p + l * 4);
    float4 bq = *(const float4*)(p + 256 + l * 4);
    float s = a.x * a.x + a.y * a.y + a.z * a.z + a.w * a.w
            + bq.x * bq.x + bq.y * bq.y + bq.z * bq.z + bq.w * bq.w;
#pragma unroll
    for (int off = 32; off > 0; off >>= 1) s += __shfl_xor(s, off, 64);
    float n = fmaxf(sqrtf(s), 1e-12f);
    float rn = 1.0f / n;
    ushort r0[4] = {f2bf(a.x * rn), f2bf(a.y * rn), f2bf(a.z * rn), f2bf(a.w * rn)};
    ushort r1[4] = {f2bf(bq.x * rn), f2bf(bq.y * rn), f2bf(bq.z * rn), f2bf(bq.w * rn)};
    *(uint2*)(cbbf + (size_t)row * DD + l * 4)       = *(const uint2*)r0;
    *(uint2*)(cbbf + (size_t)row * DD + 256 + l * 4) = *(const uint2*)r1;
    if (l == 0) nrm[row] = n;
}

// ---------------- MFMA candidate pass: 8-phase, row-split half-tiles ----------------
// Half-tile = 128 rows x 128 B (full BK) -> whole-cacheline staging. Slot swizzle
// phys = slot ^ (row&7) within each 128-B row; linear gload_lds dest with the
// inverse permutation folded into the per-lane global source (rule #21).
// Stage placement: B(t+1) in P1/P2 (B region read every phase -> only cross-set
// staging legal); A(t+2) in P4 (A region reads retire at P3's lgkm+barrier).
// One counted gate vmcnt(4) per tile (leaves A(t+2) in flight); vmcnt(0) only
// in the last 2 tiles.
__global__ __launch_bounds__(512, 2) void eq_gemm_topk(
    const ushort* __restrict__ xbf, const ushort* __restrict__ cbbf,
    float* __restrict__ candval, int* __restrict__ candidx) {
    __shared__ __align__(16) char LDS[131072];   // A: 2set x 2half x 16KB; B same @65536
    const int tid = threadIdx.x;
    const int lane = tid & 63;
    const int w = tid >> 6;          // 0..7
    const int wm = w >> 2;           // 0..1  -> 128 vocab rows
    const int wn = w & 3;            // 0..3  -> 64 x rows
    const int c = lane & 15, q = lane >> 4;

    // block mapping: each XCD's 32 blocks share one vsplit's 2MB cb panel in L2
    const int bid = blockIdx.x;                  // 0..255
    const int vsplit = (bid & 7) >> 1;
    const int xtile  = ((bid >> 3) << 1) | (bid & 1);
    const int xbase  = xtile * BN;
    const int vsbase = vsplit * VCH;

    const char* gA = (const char*)cbbf + (size_t)vsbase * 1024;   // 1024 B per row
    const char* gB = (const char*)xbf  + (size_t)xbase  * 1024;
    // staging: unit u = w*64+lane (+512 for 2nd load) -> row u>>3, phys slot u&7,
    // logical slot = (u&7) ^ ((u>>3)&7); w*8 == 0 mod 8 so lane expression only
    const int thrOff = (w * 8 + (lane >> 3)) * 1024
                     + (((lane & 7) ^ ((lane >> 3) & 7)) << 4);
    const int wbase = w * 1024;
    // read side: row r (r&7 == c&7), logical slot s*4+q at phys (s*4+q)^(r&7)
    const int sw0 = (q ^ (c & 7)) << 4;
    const int sw1 = ((4 + q) ^ (c & 7)) << 4;
    const int aoff0 = wm * 16384 + c * 128 + sw0;
    const int aoff1 = wm * 16384 + c * 128 + sw1;
    const int bbase = 65536 + (wn >> 1) * 16384 + ((wn & 1) * 64 + c) * 128;
    const int boff0 = bbase + sw0;
    const int boff1 = bbase + sw1;

#define STAGE_A(lin2, h) do { int _l = (lin2); if (_l < NTILE) { \
        const char* _s = gA + ((_l >> 3) * 262144 + (h) * 131072 + (_l & 7) * 128) + thrOff; \
        char* _d = (char*)LDS + ((_l & 1) * 32768 + (h) * 16384 + wbase); \
        GLD_LDS(_s, _d); GLD_LDS(_s + 65536, _d + 8192); } } while (0)
#define STAGE_B(lin2, h) do { int _l = (lin2); if (_l < NTILE) { \
        const char* _s = gB + ((h) * 131072 + (_l & 7) * 128) + thrOff; \
        char* _d = (char*)LDS + (65536 + (_l & 1) * 32768 + (h) * 16384 + wbase); \
        GLD_LDS(_s, _d); GLD_LDS(_s + 65536, _d + 8192); } } while (0)

    int t1k[4], t2k[4];
#pragma unroll
    for (int nj = 0; nj < 4; ++nj) { t1k[nj] = 0x80000000; t2k[nj] = 0x80000000; }

    f32x4 acc[8][4];

    // prologue: A(0),B(0),A(1); drain A(0)+B(0), leave A(1) in flight
    STAGE_A(0, 0); STAGE_A(0, 1);
    STAGE_B(0, 0); STAGE_B(0, 1);
    STAGE_A(1, 0); STAGE_A(1, 1);
    VM4(); BAR();

    for (int lin = 0; lin < NTILE; ++lin) {
        const int set = (lin & 1) * 32768;
        if ((lin & 7) == 0) {
#pragma unroll
            for (int mi = 0; mi < 8; ++mi)
#pragma unroll
                for (int nj = 0; nj < 4; ++nj) acc[mi][nj] = (f32x4){0.f, 0.f, 0.f, 0.f};
        }
        bf16x8 af[8], bf0, bf1;
        // ---- phase 1: s=0, nj 0/1; stage B-half0(t+1) ----
#pragma unroll
        for (int mi = 0; mi < 8; ++mi)
            af[mi] = *(const bf16x8*)(LDS + set + aoff0 + mi * 2048);
        bf0 = *(const bf16x8*)(LDS + set + boff0);
        bf1 = *(const bf16x8*)(LDS + set + boff0 + 2048);
        STAGE_B(lin + 1, 0);
        BAR(); LGKM0();
        __builtin_amdgcn_s_setprio(1);
#pragma unroll
        for (int mi = 0; mi < 8; ++mi) {
            acc[mi][0] = __builtin_amdgcn_mfma_f32_16x16x32_bf16(af[mi], bf0, acc[mi][0], 0, 0, 0);
            acc[mi][1] = __builtin_amdgcn_mfma_f32_16x16x32_bf16(af[mi], bf1, acc[mi][1], 0, 0, 0);
        }
        __builtin_amdgcn_s_setprio(0);
        BAR();
        // ---- phase 2: s=0, nj 2/3; stage B-half1(t+1) ----
        bf0 = *(const bf16x8*)(LDS + set + boff0 + 4096);
        bf1 = *(const bf16x8*)(LDS + set + boff0 + 6144);
        STAGE_B(lin + 1, 1);
        BAR(); LGKM0();
        __builtin_amdgcn_s_setprio(1);
#pragma unroll
        for (int mi = 0; mi < 8; ++mi) {
            acc[mi][2] = __builtin_amdgcn_mfma_f32_16x16x32_bf16(af[mi], bf0, acc[mi][2], 0, 0, 0);
            acc[mi][3] = __builtin_amdgcn_mfma_f32_16x16x32_bf16(af[mi], bf1, acc[mi][3], 0, 0, 0);
        }
        __builtin_amdgcn_s_setprio(0);
        BAR();
        // ---- phase 3: s=1, nj 0/1 (no stage) ----
#pragma unroll
        for (int mi = 0; mi < 8; ++mi)
            af[mi] = *(const bf16x8*)(LDS + set + aoff1 + mi * 2048);
        bf0 = *(const bf16x8*)(LDS + set + boff1);
        bf1 = *(const bf16x8*)(LDS + set + boff1 + 2048);
        BAR(); LGKM0();
        __builtin_amdgcn_s_setprio(1);
#pragma unroll
        for (int mi = 0; mi < 8; ++mi) {
            acc[mi][0] = __builtin_amdgcn_mfma_f32_16x16x32_bf16(af[mi], bf0, acc[mi][0], 0, 0, 0);
            acc[mi][1] = __builtin_amdgcn_mfma_f32_16x16x32_bf16(af[mi], bf1, acc[mi][1], 0, 0, 0);
        }
        __builtin_amdgcn_s_setprio(0);
        BAR();
        // ---- phase 4: s=1, nj 2/3; stage A(t+2) both halves; counted gate ----
        bf0 = *(const bf16x8*)(LDS + set + boff1 + 4096);
        bf1 = *(const bf16x8*)(LDS + set + boff1 + 6144);
        STAGE_A(lin + 2, 0);
        STAGE_A(lin + 2, 1);
        if (lin < 62) { VM4(); } else { VM0(); }
        BAR(); LGKM0();
        __builtin_amdgcn_s_setprio(1);
#pragma unroll
        for (int mi = 0; mi < 8; ++mi) {
            acc[mi][2] = __builtin_amdgcn_mfma_f32_16x16x32_bf16(af[mi], bf0, acc[mi][2], 0, 0, 0);
            acc[mi][3] = __builtin_amdgcn_mfma_f32_16x16x32_bf16(af[mi], bf1, acc[mi][3], 0, 0, 0);
        }
        __builtin_amdgcn_s_setprio(0);
        BAR();
        // ---- chunk fold: packed-key top-2 (5 VALU/value) ----
        if ((lin & 7) == 7) {
            const int chb = (lin >> 3) << 5;
#pragma unroll
            for (int nj = 0; nj < 4; ++nj)
#pragma unroll
                for (int mi = 0; mi < 8; ++mi)
#pragma unroll
                    for (int r = 0; r < 4; ++r) {
                        int key = (__float_as_int(acc[mi][nj][r]) & (int)0xFFFFFF00)
                                | (chb + mi * 4 + r);
                        int mn = t1k[nj] < key ? t1k[nj] : key;
                        t1k[nj] = t1k[nj] < key ? key : t1k[nj];
                        t2k[nj] = t2k[nj] < mn ? mn : t2k[nj];
                    }
        }
    }
    // decode keys -> (value, vocab idx), exact merge across the 4 q-lanes
#pragma unroll
    for (int nj = 0; nj < 4; ++nj) {
        int k1 = t1k[nj], k2 = t2k[nj];
        float t1v = __int_as_float(k1 & (int)0xFFFFFF00);
        float t2v = __int_as_float(k2 & (int)0xFFFFFF00);
        int l1 = k1 & 255, l2 = k2 & 255;
        int t1i = vsbase + ((l1 >> 5) << 8) + (wm << 7) + (((l1 >> 2) & 7) << 4) + (q << 2) + (l1 & 3);
        int t2i = vsbase + ((l2 >> 5) << 8) + (wm << 7) + (((l2 >> 2) & 7) << 4) + (q << 2) + (l2 & 3);
#pragma unroll
        for (int off = 16; off <= 32; off <<= 1) {
            float o1v = __shfl_xor(t1v, off, 64); int o1i = __shfl_xor(t1i, off, 64);
            float o2v = __shfl_xor(t2v, off, 64); int o2i = __shfl_xor(t2i, off, 64);
            bool wbest = (t1v > o1v) || (t1v == o1v && t1i < o1i);
            float m1 = wbest ? t1v : o1v;  int m1i = wbest ? t1i : o1i;
            float ca = wbest ? o1v : t1v;  int cai = wbest ? o1i : t1i;
            float cw = wbest ? t2v : o2v;  int cwi = wbest ? t2i : o2i;
            bool s2 = (ca > cw) || (ca == cw && cai < cwi);
            t1v = m1;           t1i = m1i;
            t2v = s2 ? ca : cw; t2i = s2 ? cai : cwi;
        }
        if (q == 0) {
            int list = vsplit * 2 + wm;
            int row = xbase + wn * 64 + nj * 16 + c;
            size_t base = ((size_t)list * NROW + row) * 2;
            candval[base] = t1v; candval[base + 1] = t2v;
            candidx[base] = t1i; candidx[base + 1] = t2i;
        }
    }
#undef STAGE_A
#undef STAGE_B
}

// ---------------- fp64 rescore with margin prefilter (+ optional fused z_q gather) ----------------
template <bool FUSE_ZQ>
__device__ __forceinline__ void rescore_body(
    const float* __restrict__ x, const float* __restrict__ cb,
    const float* __restrict__ cbnorm,
    const float* __restrict__ candval, const int* __restrict__ candidx,
    float* __restrict__ out, float* __restrict__ maxsim, int* __restrict__ counts) {
    int w = threadIdx.x >> 6, l = threadIdx.x & 63;
    int row = blockIdx.x * 4 + w;

    const float4* X4 = (const float4*)(x + (size_t)row * DD);
    float4 xa = X4[l], xb = X4[l + 64];
    float s2 = xa.x * xa.x + xa.y * xa.y + xa.z * xa.z + xa.w * xa.w
             + xb.x * xb.x + xb.y * xb.y + xb.z * xb.z + xb.w * xb.w;
#pragma unroll
    for (int off = 32; off > 0; off >>= 1) s2 += __shfl_xor(s2, off, 64);
    float xn = fmaxf(sqrtf(s2), 1e-12f);
    double xd[8] = {(double)(xa.x / xn), (double)(xa.y / xn), (double)(xa.z / xn),
                    (double)(xa.w / xn), (double)(xb.x / xn), (double)(xb.y / xn),
                    (double)(xb.z / xn), (double)(xb.w / xn)};

    float cv[16]; int ci[16];
#pragma unroll
    for (int t = 0; t < 16; ++t) {
        size_t b = ((size_t)(t >> 1) * NROW + row) * 2 + (t & 1);
        cv[t] = candval[b]; ci[t] = candidx[b];
    }
    float bv1 = cv[0];
#pragma unroll
    for (int t = 1; t < 16; ++t) bv1 = fmaxf(bv1, cv[t]);
    // candval scale is ||x||*sim; bf16 noise ~1e-4*||x|| + 3e-5 key trunc -> 2e-3 covers
    float margin = 2e-3f * xn;

    double best = -1e300; int bi = 1 << 30;
    for (int t = 0; t < 16; ++t) {
        if (cv[t] >= bv1 - margin) {                 // wave-uniform branch
            float n = cbnorm[ci[t]];
            const float4* C4 = (const float4*)(cb + (size_t)ci[t] * DD);
            float4 ca = C4[l], cb4 = C4[l + 64];
            double a = xd[0] * (double)(ca.x / n) + xd[1] * (double)(ca.y / n)
                     + xd[2] * (double)(ca.z / n) + xd[3] * (double)(ca.w / n)
                     + xd[4] * (double)(cb4.x / n) + xd[5] * (double)(cb4.y / n)
                     + xd[6] * (double)(cb4.z / n) + xd[7] * (double)(cb4.w / n);
#pragma unroll
            for (int off = 32; off > 0; off >>= 1) a += __shfl_xor(a, off, 64);
            bool better = (a > best) || (a == best && ci[t] < bi);
            best = better ? a : best;     // wave-uniform after reduction
            bi = better ? ci[t] : bi;
        }
    }
    if (l == 0) {
        out[OUT_IDX + row] = (float)bi;
        maxsim[row] = (float)best;
        atomicAdd(counts + bi, 1);
    }
    if (FUSE_ZQ) {
        const float4* src = (const float4*)(cb + (size_t)bi * DD);
        float4* dst = (float4*)(out + (size_t)row * DD);
        dst[l] = src[l];
        dst[l + 64] = src[l + 64];
    }
}

__global__ void eq_rescore(const float* __restrict__ x, const float* __restrict__ cb,
                           const float* __restrict__ cbnorm,
                           const float* __restrict__ candval, const int* __restrict__ candidx,
                           float* __restrict__ out, float* __restrict__ maxsim,
                           int* __restrict__ counts) {
    rescore_body<false>(x, cb, cbnorm, candval, candidx, out, maxsim, counts);
}

__global__ void eq_rescore_fused(const float* __restrict__ x, const float* __restrict__ cb,
                                 const float* __restrict__ cbnorm,
                                 const float* __restrict__ candval, const int* __restrict__ candidx,
                                 float* __restrict__ out, float* __restrict__ maxsim,
                                 int* __restrict__ counts) {
    rescore_body<true>(x, cb, cbnorm, candval, candidx, out, maxsim, counts);
}

// ---------------- z_q gather (fallback path only) ----------------
__global__ void eq_gather(const float* __restrict__ cb, float* __restrict__ out) {
    int w = threadIdx.x >> 6, l = threadIdx.x & 63;
    int row = blockIdx.x * 4 + w;
    int bi = (int)out[OUT_IDX + row];
    const float4* src = (const float4*)(cb + (size_t)bi * DD);
    float4* dst = (float4*)(out + (size_t)row * DD);
    dst[l] = src[l];
    dst[l + 64] = src[l + 64];
}

// ---------------- entropy + mean ----------------
__global__ void eq_entropy_mean(const int* __restrict__ counts,
                                const float* __restrict__ maxsim,
                                float* __restrict__ out) {
    __shared__ float red[16];
    int tid = threadIdx.x;   // 1024
    float s = 0.f;
    for (int b = tid; b < VOCAB; b += 1024) {
        int c = counts[b];
        if (c > 0) {
            float p = (float)c * (1.0f / 16384.0f);
            s += p * logf(p);
        }
    }
#pragma unroll
    for (int off = 32; off > 0; off >>= 1) s += __shfl_down(s, off, 64);
    if ((tid & 63) == 0) red[tid >> 6] = s;
    __syncthreads();
    if (tid == 0) {
        float t = 0.f;
#pragma unroll
        for (int i = 0; i < 16; ++i) t += red[i];
        out[OUT_ENT] = -t;
    }
    __syncthreads();
    float m = 0.f;
    for (int i = tid; i < NROW; i += 1024) m += maxsim[i];
#pragma unroll
    for (int off = 32; off > 0; off >>= 1) m += __shfl_down(m, off, 64);
    if ((tid & 63) == 0) red[tid >> 6] = m;
    __syncthreads();
    if (tid == 0) {
        float t = 0.f;
#pragma unroll
        for (int i = 0; i < 16; ++i) t += red[i];
        out[OUT_MEAN] = t * (1.0f / 16384.0f);
    }
}

extern "C" void kernel_launch(void* const* d_in, const int* in_sizes, int n_in,
                              void* d_out, int out_size, void* d_ws, size_t ws_size,
                              hipStream_t stream) {
    const float* x  = (const float*)d_in[0];
    const float* cb = (const float*)d_in[1];
    float* out = (float*)d_out;
    float* wsf = (float*)d_ws;
    int*   wsi = (int*)d_ws;

    float* cbnorm = wsf + WS_CBNORM;
    float* maxsim = wsf + WS_MAXSIM;
    int*   counts = wsi + WS_COUNTS;

    ushort* xbf   = (ushort*)out;                 // scratch in out
    ushort* cbbf  = (ushort*)(out + CBBF_W);

    const bool fused = ws_size >= WS_NEED_BYTES;  // deterministic per deployment
    float* candv = fused ? (wsf + WS_CANDV) : (out + CANDV_W);
    int*   candi = fused ? (wsi + WS_CANDI) : (int*)(out + CANDI_W);

    eq_prep<<<6144, 256, 0, stream>>>(x, cb, xbf, cbbf, cbnorm, counts);

    eq_gemm_topk<<<256, 512, 0, stream>>>(xbf, cbbf, candv, candi);

    if (fused) {
        eq_rescore_fused<<<NROW / 4, 256, 0, stream>>>(x, cb, cbnorm, candv, candi,
                                                       out, maxsim, counts);
    } else {
        eq_rescore<<<NROW / 4, 256, 0, stream>>>(x, cb, cbnorm, candv, candi,
                                                 out, maxsim, counts);
        eq_gather<<<NROW / 4, 256, 0, stream>>>(cb, out);
    }
    eq_entropy_mean<<<1, 1024, 0, stream>>>(counts, maxsim, out);
}